// Round 1
// baseline (2220.611 us; speedup 1.0000x reference)
//
#include <hip/hip_runtime.h>
#include <math.h>

constexpr int NN = 60000;   // nodes
constexpr int NE = 480000;  // edges
constexpr int NB = 128;     // graphs

__device__ __forceinline__ float f4c(const float4 v, int k) {
    return k == 0 ? v.x : (k == 1 ? v.y : (k == 2 ? v.z : v.w));
}

// ---------------- edge features + forward-in-time compaction ----------------
__global__ __launch_bounds__(256) void edge_compact_k(
    const float* __restrict__ x, const int* __restrict__ send, const int* __restrict__ recv,
    float* __restrict__ e8, int* __restrict__ cse, int* __restrict__ cre, int* __restrict__ ecnt)
{
    int e = blockIdx.x * 256 + threadIdx.x;
    if (e >= NE) return;
    int s = send[e], r = recv[e];
    const float* xs = x + (size_t)s * 6;
    const float* xr = x + (size_t)r * 6;
    float xs3 = xs[3], xr3 = xr[3];
    if (!(xs3 <= xr3)) return;                 // masked edge contributes nothing anywhere
    float d0 = xr[0] - xs[0], d1 = xr[1] - xs[1], d2 = xr[2] - xs[2];
    float d3 = xr3 - xs3,     d4 = xr[4] - xs[4], d5 = xr[5] - xs[5];
    float dist = sqrtf(d0 * d0 + d1 * d1 + d2 * d2);
    float inv = dist > 0.f ? 1.f / dist : 0.f;
    int slot = atomicAdd(ecnt, 1);
    float4* o = (float4*)(e8 + (size_t)slot * 8);
    o[0] = make_float4(d3, d4, d5, dist);
    o[1] = make_float4(d0 * inv, d1 * inv, d2 * inv, 1.f);
    cse[slot] = s;
    cre[slot] = r;
}

// ---------------- edge message MLP (2 layers, relu) + atomic scatter-sum ----------------
// in = [h[recv](HD), h[send](HD), e(7)]  -> 256 -> 128, scatter to hout[recv]
template<int HD>
__global__ __launch_bounds__(256) void msg_k(
    const float* __restrict__ hin,
    const float* __restrict__ e8,
    const int* __restrict__ cse, const int* __restrict__ cre,
    const int* __restrict__ ecnt,
    const float* __restrict__ w1, const float* __restrict__ b1,   // [KIN,256],[256]
    const float* __restrict__ w2, const float* __restrict__ b2,   // [256,128],[128]
    float* __restrict__ hout)                                     // [NN,128] zeroed
{
    constexpr int KIN  = 2 * HD + 7;
    constexpr int KINP = (KIN + 4) & ~3;   // 20 (HD=6) / 264 (HD=128)
    __shared__ float s_in[32][KINP];
    __shared__ float s_t[32][260];
    __shared__ int   s_recv[32];

    const int Ec = *ecnt;
    const int e0 = blockIdx.x * 32;
    if (e0 >= Ec) return;
    const int tid = threadIdx.x;

    { // ---- stage inputs: 8 threads per edge ----
        const int eg = tid >> 3, sub = tid & 7;
        const int e = e0 + eg;
        if (e < Ec) {
            const int s = cse[e], r = cre[e];
            if (sub == 0) s_recv[eg] = r;
            if constexpr (HD == 128) {
                const float* hr = hin + (size_t)r * 128;
                const float* hs = hin + (size_t)s * 128;
                #pragma unroll
                for (int c = sub * 4; c < 128; c += 32) {
                    *(float4*)&s_in[eg][c]       = *(const float4*)&hr[c];
                    *(float4*)&s_in[eg][128 + c] = *(const float4*)&hs[c];
                }
                if (sub == 1) {
                    #pragma unroll
                    for (int c = 0; c < 7; ++c) s_in[eg][256 + c] = e8[(size_t)e * 8 + c];
                    s_in[eg][263] = 0.f;
                }
            } else {
                if (sub == 0) {
                    const float* hr = hin + (size_t)r * 6;
                    const float* hs = hin + (size_t)s * 6;
                    #pragma unroll
                    for (int c = 0; c < 6; ++c) { s_in[eg][c] = hr[c]; s_in[eg][6 + c] = hs[c]; }
                    #pragma unroll
                    for (int c = 0; c < 7; ++c) s_in[eg][12 + c] = e8[(size_t)e * 8 + c];
                    s_in[eg][19] = 0.f;
                }
            }
        }
    }
    __syncthreads();

    { // ---- layer 1: [32,KIN] x [KIN,256] -> s_t (relu). 4 rows x 8 cols per thread ----
        const int j0 = (tid & 31) * 8;
        const int r0 = (tid >> 5) * 4;
        float acc[4][8];
        #pragma unroll
        for (int c = 0; c < 8; ++c) {
            const float bv = b1[j0 + c];
            #pragma unroll
            for (int r = 0; r < 4; ++r) acc[r][c] = bv;
        }
        constexpr int KIN4 = KIN & ~3;
        for (int k0 = 0; k0 < KIN4; k0 += 4) {
            float4 a[4];
            #pragma unroll
            for (int r = 0; r < 4; ++r) a[r] = *(const float4*)&s_in[r0 + r][k0];
            #pragma unroll
            for (int kk = 0; kk < 4; ++kk) {
                const float4 wA = *(const float4*)&w1[(size_t)(k0 + kk) * 256 + j0];
                const float4 wB = *(const float4*)&w1[(size_t)(k0 + kk) * 256 + j0 + 4];
                #pragma unroll
                for (int r = 0; r < 4; ++r) {
                    const float ar = f4c(a[r], kk);
                    acc[r][0] += ar * wA.x; acc[r][1] += ar * wA.y;
                    acc[r][2] += ar * wA.z; acc[r][3] += ar * wA.w;
                    acc[r][4] += ar * wB.x; acc[r][5] += ar * wB.y;
                    acc[r][6] += ar * wB.z; acc[r][7] += ar * wB.w;
                }
            }
        }
        for (int k = KIN4; k < KIN; ++k) {   // tail (3 elems)
            const float4 wA = *(const float4*)&w1[(size_t)k * 256 + j0];
            const float4 wB = *(const float4*)&w1[(size_t)k * 256 + j0 + 4];
            #pragma unroll
            for (int r = 0; r < 4; ++r) {
                const float ar = s_in[r0 + r][k];
                acc[r][0] += ar * wA.x; acc[r][1] += ar * wA.y;
                acc[r][2] += ar * wA.z; acc[r][3] += ar * wA.w;
                acc[r][4] += ar * wB.x; acc[r][5] += ar * wB.y;
                acc[r][6] += ar * wB.z; acc[r][7] += ar * wB.w;
            }
        }
        #pragma unroll
        for (int r = 0; r < 4; ++r) {
            const float4 v0 = make_float4(fmaxf(acc[r][0], 0.f), fmaxf(acc[r][1], 0.f),
                                          fmaxf(acc[r][2], 0.f), fmaxf(acc[r][3], 0.f));
            const float4 v1 = make_float4(fmaxf(acc[r][4], 0.f), fmaxf(acc[r][5], 0.f),
                                          fmaxf(acc[r][6], 0.f), fmaxf(acc[r][7], 0.f));
            *(float4*)&s_t[r0 + r][j0]     = v0;
            *(float4*)&s_t[r0 + r][j0 + 4] = v1;
        }
    }
    __syncthreads();

    { // ---- layer 2: [32,256] x [256,128] -> relu -> atomic scatter. 4 rows x 4 cols ----
        const int j0 = (tid & 31) * 4;
        const int r0 = (tid >> 5) * 4;
        float acc[4][4];
        #pragma unroll
        for (int c = 0; c < 4; ++c) {
            const float bv = b2[j0 + c];
            #pragma unroll
            for (int r = 0; r < 4; ++r) acc[r][c] = bv;
        }
        for (int k0 = 0; k0 < 256; k0 += 4) {
            float4 t[4];
            #pragma unroll
            for (int r = 0; r < 4; ++r) t[r] = *(const float4*)&s_t[r0 + r][k0];
            #pragma unroll
            for (int kk = 0; kk < 4; ++kk) {
                const float4 w = *(const float4*)&w2[(size_t)(k0 + kk) * 128 + j0];
                #pragma unroll
                for (int r = 0; r < 4; ++r) {
                    const float tr = f4c(t[r], kk);
                    acc[r][0] += tr * w.x; acc[r][1] += tr * w.y;
                    acc[r][2] += tr * w.z; acc[r][3] += tr * w.w;
                }
            }
        }
        #pragma unroll
        for (int r = 0; r < 4; ++r) {
            if (e0 + r0 + r >= Ec) continue;
            float* dst = hout + (size_t)s_recv[r0 + r] * 128 + j0;
            #pragma unroll
            for (int c = 0; c < 4; ++c) unsafeAtomicAdd(dst + c, fmaxf(acc[r][c], 0.f));
        }
    }
}

// ---------------- node update MLP: 128 -> 128 -> 64 ----------------
__global__ __launch_bounds__(256) void upd_k(
    const float* __restrict__ hin,                                 // [NN,128]
    const float* __restrict__ w1, const float* __restrict__ b1,    // [128,128]
    const float* __restrict__ w2, const float* __restrict__ b2,    // [128,64]
    float* __restrict__ hout)                                      // [NN,64]
{
    __shared__ float s_in[32][132];
    __shared__ float s_t[32][132];
    const int tid = threadIdx.x;
    const int n0 = blockIdx.x * 32;
    {
        const int ng = tid >> 3, sub = tid & 7;
        const float* hr = hin + (size_t)(n0 + ng) * 128;
        #pragma unroll
        for (int c = sub * 4; c < 128; c += 32)
            *(float4*)&s_in[ng][c] = *(const float4*)&hr[c];
    }
    __syncthreads();
    { // layer1: 128 cols, 4 rows x 4 cols per thread
        const int j0 = (tid & 31) * 4;
        const int r0 = (tid >> 5) * 4;
        float acc[4][4];
        #pragma unroll
        for (int c = 0; c < 4; ++c) {
            const float bv = b1[j0 + c];
            #pragma unroll
            for (int r = 0; r < 4; ++r) acc[r][c] = bv;
        }
        for (int k0 = 0; k0 < 128; k0 += 4) {
            float4 a[4];
            #pragma unroll
            for (int r = 0; r < 4; ++r) a[r] = *(const float4*)&s_in[r0 + r][k0];
            #pragma unroll
            for (int kk = 0; kk < 4; ++kk) {
                const float4 w = *(const float4*)&w1[(size_t)(k0 + kk) * 128 + j0];
                #pragma unroll
                for (int r = 0; r < 4; ++r) {
                    const float ar = f4c(a[r], kk);
                    acc[r][0] += ar * w.x; acc[r][1] += ar * w.y;
                    acc[r][2] += ar * w.z; acc[r][3] += ar * w.w;
                }
            }
        }
        #pragma unroll
        for (int r = 0; r < 4; ++r)
            *(float4*)&s_t[r0 + r][j0] = make_float4(fmaxf(acc[r][0], 0.f), fmaxf(acc[r][1], 0.f),
                                                     fmaxf(acc[r][2], 0.f), fmaxf(acc[r][3], 0.f));
    }
    __syncthreads();
    { // layer2: 64 cols, 2 rows x 4 cols per thread
        const int j0 = (tid & 15) * 4;
        const int r0 = (tid >> 4) * 2;
        float acc[2][4];
        #pragma unroll
        for (int c = 0; c < 4; ++c) {
            const float bv = b2[j0 + c];
            acc[0][c] = bv; acc[1][c] = bv;
        }
        for (int k0 = 0; k0 < 128; k0 += 4) {
            float4 t0 = *(const float4*)&s_t[r0][k0];
            float4 t1 = *(const float4*)&s_t[r0 + 1][k0];
            #pragma unroll
            for (int kk = 0; kk < 4; ++kk) {
                const float4 w = *(const float4*)&w2[(size_t)(k0 + kk) * 64 + j0];
                const float a0 = f4c(t0, kk), a1 = f4c(t1, kk);
                acc[0][0] += a0 * w.x; acc[0][1] += a0 * w.y; acc[0][2] += a0 * w.z; acc[0][3] += a0 * w.w;
                acc[1][0] += a1 * w.x; acc[1][1] += a1 * w.y; acc[1][2] += a1 * w.z; acc[1][3] += a1 * w.w;
            }
        }
        #pragma unroll
        for (int r = 0; r < 2; ++r)
            *(float4*)&hout[(size_t)(n0 + r0 + r) * 64 + j0] =
                make_float4(fmaxf(acc[r][0], 0.f), fmaxf(acc[r][1], 0.f),
                            fmaxf(acc[r][2], 0.f), fmaxf(acc[r][3], 0.f));
    }
}

// ---------------- SAGE neighbor scatter: nbr[recv] += h[send]; cnt[recv] += 1 ----------------
__global__ __launch_bounds__(256) void sage_scatter_k(
    const float* __restrict__ h, const int* __restrict__ cse, const int* __restrict__ cre,
    const int* __restrict__ ecnt, float* __restrict__ nbr, float* __restrict__ cnt)
{
    const int gid = blockIdx.x * 256 + threadIdx.x;
    const int e = gid >> 4, c0 = (gid & 15) * 4;
    if (e >= *ecnt) return;
    const int s = cse[e], r = cre[e];
    const float4 hv = *(const float4*)&h[(size_t)s * 64 + c0];
    float* dst = nbr + (size_t)r * 64 + c0;
    unsafeAtomicAdd(dst + 0, hv.x); unsafeAtomicAdd(dst + 1, hv.y);
    unsafeAtomicAdd(dst + 2, hv.z); unsafeAtomicAdd(dst + 3, hv.w);
    if (c0 == 0) unsafeAtomicAdd(cnt + r, 1.f);
}

// ---------------- SAGE node transform + l2norm + relu, fused graph pooling ----------------
__global__ __launch_bounds__(256) void sage_node_k(
    const float* __restrict__ h, const float* __restrict__ nbr, const float* __restrict__ cnt,
    const int* __restrict__ seg,
    const float* __restrict__ sw, const float* __restrict__ sb,    // [128,128],[128]
    float* __restrict__ pmax, float* __restrict__ psum, float* __restrict__ npn)
{
    __shared__ float s_in[16][132];
    __shared__ float s_t[16][132];
    __shared__ float s_inv[16];
    __shared__ int   s_seg[16];
    const int tid = threadIdx.x;
    const int n0 = blockIdx.x * 16;
    {
        const int ng = tid >> 4, sub = tid & 15;
        const int n = n0 + ng;
        const int c = sub * 4;
        *(float4*)&s_in[ng][c] = *(const float4*)&h[(size_t)n * 64 + c];
        const float inv = 1.f / fmaxf(cnt[n], 1.f);
        const float4 nb = *(const float4*)&nbr[(size_t)n * 64 + c];
        s_in[ng][64 + c + 0] = nb.x * inv; s_in[ng][64 + c + 1] = nb.y * inv;
        s_in[ng][64 + c + 2] = nb.z * inv; s_in[ng][64 + c + 3] = nb.w * inv;
        if (sub == 0) s_seg[ng] = seg[n];
    }
    __syncthreads();
    { // dense 128x128: 1 col x 8 rows per thread
        const int j = tid & 127;
        const int r0 = (tid >> 7) * 8;
        float acc[8];
        const float bv = sb[j];
        #pragma unroll
        for (int r = 0; r < 8; ++r) acc[r] = bv;
        for (int k0 = 0; k0 < 128; k0 += 4) {
            float4 a[8];
            #pragma unroll
            for (int r = 0; r < 8; ++r) a[r] = *(const float4*)&s_in[r0 + r][k0];
            #pragma unroll
            for (int kk = 0; kk < 4; ++kk) {
                const float w = sw[(size_t)(k0 + kk) * 128 + j];
                #pragma unroll
                for (int r = 0; r < 8; ++r) acc[r] += f4c(a[r], kk) * w;
            }
        }
        #pragma unroll
        for (int r = 0; r < 8; ++r) s_t[r0 + r][j] = acc[r];
    }
    __syncthreads();
    if (tid < 16) {
        float ss = 0.f;
        for (int j = 0; j < 128; ++j) { const float v = s_t[tid][j]; ss += v * v; }
        s_inv[tid] = 1.f / sqrtf(fmaxf(ss, 1e-12f));
    }
    __syncthreads();
    {
        const int j = tid & 127;
        const int r0 = (tid >> 7) * 8;
        #pragma unroll
        for (int r = 0; r < 8; ++r) {
            const int n = r0 + r;
            const float g = fmaxf(s_t[n][j] * s_inv[n], 0.f);
            const int sg = s_seg[n];
            unsafeAtomicAdd(&psum[(size_t)sg * 128 + j], g);
            atomicMax((unsigned int*)&pmax[(size_t)sg * 128 + j], __float_as_uint(g));
        }
    }
    if (tid < 16) unsafeAtomicAdd(&npn[s_seg[tid]], 1.f);
}

// ---------------- decoder (2x dense+lrelu+BN) + 3 linear heads + final assembly ----------------
__global__ __launch_bounds__(256) void dec_heads_k(
    const float* __restrict__ pmax, const float* __restrict__ psum, const float* __restrict__ npn,
    const float* __restrict__ d0w, const float* __restrict__ d0b,
    const float* __restrict__ g0, const float* __restrict__ be0,
    const float* __restrict__ m0, const float* __restrict__ v0,
    const float* __restrict__ d1w, const float* __restrict__ d1b,
    const float* __restrict__ g1, const float* __restrict__ be1,
    const float* __restrict__ m1, const float* __restrict__ v1,
    const float* __restrict__ lw0, const float* __restrict__ lb0,
    const float* __restrict__ lw1, const float* __restrict__ lb1,
    const float* __restrict__ lwo, const float* __restrict__ lbo,
    const float* __restrict__ aw0, const float* __restrict__ ab0,
    const float* __restrict__ aw1, const float* __restrict__ ab1,
    const float* __restrict__ awo, const float* __restrict__ abo,
    const float* __restrict__ sw0, const float* __restrict__ sb0,
    const float* __restrict__ sw1, const float* __restrict__ sb1,
    const float* __restrict__ swo, const float* __restrict__ sbo,
    const float* __restrict__ ascw, const float* __restrict__ ascb,
    float* __restrict__ out)
{
    __shared__ float z0[384];
    __shared__ float z1[1024];
    __shared__ float z2[512];
    __shared__ float ha[192];
    __shared__ float hb[192];
    __shared__ float fin[8];
    const int b = blockIdx.x, tid = threadIdx.x;
    if (tid < 128) {
        const float pm = pmax[(size_t)b * 128 + tid];
        const float ps = psum[(size_t)b * 128 + tid];
        const float nv = fmaxf(npn[b], 1.f);
        z0[tid] = pm; z0[128 + tid] = ps / nv; z0[256 + tid] = ps;
    }
    __syncthreads();
    { // dec0: 384 -> 1024, lrelu(0.15), BN(eps=1e-3)
        float acc[4] = { d0b[tid], d0b[tid + 256], d0b[tid + 512], d0b[tid + 768] };
        for (int k = 0; k < 384; ++k) {
            const float zk = z0[k];
            const float* wr = d0w + (size_t)k * 1024 + tid;
            acc[0] += zk * wr[0]; acc[1] += zk * wr[256]; acc[2] += zk * wr[512]; acc[3] += zk * wr[768];
        }
        #pragma unroll
        for (int i = 0; i < 4; ++i) {
            const int j = tid + 256 * i;
            float v = acc[i] > 0.f ? acc[i] : 0.15f * acc[i];
            v = (v - m0[j]) * (1.f / sqrtf(v0[j] + 1e-3f)) * g0[j] + be0[j];
            z1[j] = v;
        }
    }
    __syncthreads();
    { // dec1: 1024 -> 512
        float acc[2] = { d1b[tid], d1b[tid + 256] };
        for (int k = 0; k < 1024; ++k) {
            const float zk = z1[k];
            const float* wr = d1w + (size_t)k * 512 + tid;
            acc[0] += zk * wr[0]; acc[1] += zk * wr[256];
        }
        #pragma unroll
        for (int i = 0; i < 2; ++i) {
            const int j = tid + 256 * i;
            float v = acc[i] > 0.f ? acc[i] : 0.15f * acc[i];
            v = (v - m1[j]) * (1.f / sqrtf(v1[j] + 1e-3f)) * g1[j] + be1[j];
            z2[j] = v;
        }
    }
    __syncthreads();
    if (tid < 192) { // heads layer 0 (linear, no act): 512 -> 64 for 3 heads
        const int hd = tid >> 6, j = tid & 63;
        const float* w0 = hd == 0 ? lw0 : (hd == 1 ? aw0 : sw0);
        const float* b0 = hd == 0 ? lb0 : (hd == 1 ? ab0 : sb0);
        float acc = b0[j];
        for (int k = 0; k < 512; ++k) acc += z2[k] * w0[(size_t)k * 64 + j];
        ha[tid] = acc;
    }
    __syncthreads();
    if (tid < 192) { // heads layer 1 (linear): 64 -> 64
        const int hd = tid >> 6, j = tid & 63;
        const float* w1p = hd == 0 ? lw1 : (hd == 1 ? aw1 : sw1);
        const float* b1p = hd == 0 ? lb1 : (hd == 1 ? ab1 : sb1);
        const float* src = &ha[hd * 64];
        float acc = b1p[j];
        for (int k = 0; k < 64; ++k) acc += src[k] * w1p[(size_t)k * 64 + j];
        hb[tid] = acc;
    }
    __syncthreads();
    if (tid < 5) { // head outputs: loge(1), ang(2), sig(2)
        float acc;
        if (tid == 0) { acc = lbo[0]; for (int k = 0; k < 64; ++k) acc += hb[k] * lwo[k]; }
        else if (tid < 3) { const int c = tid - 1; acc = abo[c]; for (int k = 0; k < 64; ++k) acc += hb[64 + k] * awo[k * 2 + c]; }
        else { const int c = tid - 3; acc = sbo[c]; for (int k = 0; k < 64; ++k) acc += hb[128 + k] * swo[k * 2 + c]; }
        fin[tid] = acc;
    }
    __syncthreads();
    if (tid == 0) {
        const float a0 = fin[1], a1 = fin[2];
        const float q0 = a0 * ascw[0] + a1 * ascw[2] + ascb[0];
        const float q1 = a0 * ascw[1] + a1 * ascw[3] + ascb[1];
        const float zen = 1.f / (1.f + expf(-q0));
        const float azi = 1.f / (1.f + expf(-q1));
        const float PI = 3.14159265358979323846f;
        float* o = out + (size_t)b * 5;
        o[0] = fin[0];
        o[1] = zen * PI;
        o[2] = azi * 2.f * PI;
        o[3] = fabsf(fin[3]) + 1e-5f;
        o[4] = fabsf(fin[4]) + 1e-5f;
    }
}

extern "C" void kernel_launch(void* const* d_in, const int* in_sizes, int n_in,
                              void* d_out, int out_size, void* d_ws, size_t ws_size,
                              hipStream_t stream)
{
    const float* x    = (const float*)d_in[0];
    const int* send   = (const int*)d_in[1];
    const int* recv   = (const int*)d_in[2];
    const int* seg    = (const int*)d_in[3];
    const float* m0w1 = (const float*)d_in[4];
    const float* m0b1 = (const float*)d_in[5];
    const float* m0w2 = (const float*)d_in[6];
    const float* m0b2 = (const float*)d_in[7];
    const float* m1w1 = (const float*)d_in[8];
    const float* m1b1 = (const float*)d_in[9];
    const float* m1w2 = (const float*)d_in[10];
    const float* m1b2 = (const float*)d_in[11];
    const float* uw1  = (const float*)d_in[12];
    const float* ub1  = (const float*)d_in[13];
    const float* uw2  = (const float*)d_in[14];
    const float* ub2  = (const float*)d_in[15];
    const float* sgw  = (const float*)d_in[16];
    const float* sgb  = (const float*)d_in[17];
    const float* d0w  = (const float*)d_in[18];
    const float* d0b  = (const float*)d_in[19];
    const float* bn0g = (const float*)d_in[20];
    const float* bn0b = (const float*)d_in[21];
    const float* bn0m = (const float*)d_in[22];
    const float* bn0v = (const float*)d_in[23];
    const float* d1w  = (const float*)d_in[24];
    const float* d1b  = (const float*)d_in[25];
    const float* bn1g = (const float*)d_in[26];
    const float* bn1b = (const float*)d_in[27];
    const float* bn1m = (const float*)d_in[28];
    const float* bn1v = (const float*)d_in[29];
    const float* lw0  = (const float*)d_in[30];
    const float* lb0  = (const float*)d_in[31];
    const float* lw1  = (const float*)d_in[32];
    const float* lb1  = (const float*)d_in[33];
    const float* lwo  = (const float*)d_in[34];
    const float* lbo  = (const float*)d_in[35];
    const float* aw0  = (const float*)d_in[36];
    const float* ab0  = (const float*)d_in[37];
    const float* aw1  = (const float*)d_in[38];
    const float* ab1  = (const float*)d_in[39];
    const float* awo  = (const float*)d_in[40];
    const float* abo  = (const float*)d_in[41];
    const float* sw0  = (const float*)d_in[42];
    const float* sb0  = (const float*)d_in[43];
    const float* sw1  = (const float*)d_in[44];
    const float* sb1  = (const float*)d_in[45];
    const float* swo  = (const float*)d_in[46];
    const float* sbo  = (const float*)d_in[47];
    const float* ascw = (const float*)d_in[48];
    const float* ascb = (const float*)d_in[49];

    float* ws = (float*)d_ws;
    float* e8   = ws;                                   // [E,8] compacted edge feats
    float* h1   = e8 + (size_t)NE * 8;                  // [N,128]
    float* h2   = h1 + (size_t)NN * 128;                // [N,128]
    float* pool = h2 + (size_t)NN * 128;                // pmax|psum|npn
    float* pmax = pool;
    float* psum = pool + (size_t)NB * 128;
    float* npn  = psum + (size_t)NB * 128;
    int* cse    = (int*)(npn + NB);                     // [E]
    int* cre    = cse + NE;                             // [E]
    int* ecnt   = cre + NE;                             // [1]
    float* hu   = h1;                                   // [N,64]  (h1 dead after msg1)
    float* nbr  = h2;                                   // [N,64]  (h2 dead after upd)
    float* cnt  = h2 + (size_t)NN * 64;                 // [N]

    // zero accumulators: h1, h2, pools; zero edge counter
    hipMemsetAsync(h1, 0, ((size_t)NN * 256 + (size_t)NB * 257) * sizeof(float), stream);
    hipMemsetAsync(ecnt, 0, sizeof(int), stream);

    edge_compact_k<<<(NE + 255) / 256, 256, 0, stream>>>(x, send, recv, e8, cse, cre, ecnt);
    msg_k<6><<<NE / 32, 256, 0, stream>>>(x, e8, cse, cre, ecnt, m0w1, m0b1, m0w2, m0b2, h1);
    msg_k<128><<<NE / 32, 256, 0, stream>>>(h1, e8, cse, cre, ecnt, m1w1, m1b1, m1w2, m1b2, h2);
    upd_k<<<NN / 32, 256, 0, stream>>>(h2, uw1, ub1, uw2, ub2, hu);
    hipMemsetAsync(nbr, 0, (size_t)NN * 65 * sizeof(float), stream);
    sage_scatter_k<<<NE * 16 / 256, 256, 0, stream>>>(hu, cse, cre, ecnt, nbr, cnt);
    sage_node_k<<<NN / 16, 256, 0, stream>>>(hu, nbr, cnt, seg, sgw, sgb, pmax, psum, npn);
    dec_heads_k<<<NB, 256, 0, stream>>>(pmax, psum, npn,
        d0w, d0b, bn0g, bn0b, bn0m, bn0v,
        d1w, d1b, bn1g, bn1b, bn1m, bn1v,
        lw0, lb0, lw1, lb1, lwo, lbo,
        aw0, ab0, aw1, ab1, awo, abo,
        sw0, sb0, sw1, sb1, swo, sbo,
        ascw, ascb, (float*)d_out);
}

// Round 2
// 1190.137 us; speedup vs baseline: 1.8658x; 1.8658x over previous
//
#include <hip/hip_runtime.h>
#include <hip/hip_bf16.h>
#include <math.h>

constexpr int NN = 60000;   // nodes
constexpr int NE = 480000;  // edges
constexpr int NB = 128;     // graphs

typedef __attribute__((ext_vector_type(8))) short  short8;
typedef __attribute__((ext_vector_type(8))) unsigned short ushort8;
typedef __attribute__((ext_vector_type(4))) float  f32x4;

__device__ __forceinline__ unsigned short f2b(float x) {
    __hip_bfloat16 h = __float2bfloat16(x);   // RNE
    return *reinterpret_cast<unsigned short*>(&h);
}
__device__ __forceinline__ float f4c(const float4 v, int k) {
    return k == 0 ? v.x : (k == 1 ? v.y : (k == 2 ? v.z : v.w));
}

// ---------------- edge features + forward-in-time compaction ----------------
__global__ __launch_bounds__(256) void edge_compact_k(
    const float* __restrict__ x, const int* __restrict__ send, const int* __restrict__ recv,
    float* __restrict__ e8, int* __restrict__ cse, int* __restrict__ cre, int* __restrict__ ecnt)
{
    int e = blockIdx.x * 256 + threadIdx.x;
    if (e >= NE) return;
    int s = send[e], r = recv[e];
    const float* xs = x + (size_t)s * 6;
    const float* xr = x + (size_t)r * 6;
    float xs3 = xs[3], xr3 = xr[3];
    if (!(xs3 <= xr3)) return;                 // masked edge contributes nothing anywhere
    float d0 = xr[0] - xs[0], d1 = xr[1] - xs[1], d2 = xr[2] - xs[2];
    float d3 = xr3 - xs3,     d4 = xr[4] - xs[4], d5 = xr[5] - xs[5];
    float dist = sqrtf(d0 * d0 + d1 * d1 + d2 * d2);
    float inv = dist > 0.f ? 1.f / dist : 0.f;
    int slot = atomicAdd(ecnt, 1);
    float4* o = (float4*)(e8 + (size_t)slot * 8);
    o[0] = make_float4(d3, d4, d5, dist);
    o[1] = make_float4(d0 * inv, d1 * inv, d2 * inv, 0.f);
    cse[slot] = s;
    cre[slot] = r;
}

// ---------------- pack weights into MFMA B-fragment order ----------------
// w [KIN][NCOL] f32 -> out[((kt*NT+nt)*64+lane)*8+i] bf16 where
// k = kt*32 + (lane>>4)*8 + i, n = nt*16 + (lane&15); zero past KIN.
__global__ __launch_bounds__(256) void pack_w_k(
    const float* __restrict__ w, unsigned short* __restrict__ out,
    int KIN, int NT, int KT, int NCOL)
{
    int idx = blockIdx.x * 256 + threadIdx.x;
    int total = KT * NT * 512;
    if (idx >= total) return;
    int i = idx & 7;
    int lane = (idx >> 3) & 63;
    int t = idx >> 9;            // kt*NT + nt
    int nt = t % NT, kt = t / NT;
    int k = kt * 32 + (lane >> 4) * 8 + i;
    int n = nt * 16 + (lane & 15);
    out[idx] = (k < KIN) ? f2b(w[(size_t)k * NCOL + n]) : (unsigned short)0;
}

// ---------------- fp32 -> bf16 bulk convert (h1 for msg1 A-operand) ----------------
__global__ __launch_bounds__(256) void f2b_k(const float* __restrict__ in,
                                             unsigned short* __restrict__ out, int n8)
{
    int i = blockIdx.x * 256 + threadIdx.x;
    if (i >= n8) return;
    const float4 a = ((const float4*)in)[i * 2];
    const float4 b = ((const float4*)in)[i * 2 + 1];
    ushort8 o;
    o[0] = f2b(a.x); o[1] = f2b(a.y); o[2] = f2b(a.z); o[3] = f2b(a.w);
    o[4] = f2b(b.x); o[5] = f2b(b.y); o[6] = f2b(b.z); o[7] = f2b(b.w);
    ((ushort8*)out)[i] = o;
}

// ---------------- MFMA edge message MLP + atomic scatter-sum ----------------
// in = [h[recv](HD), h[send](HD), e(7)] -> relu(·W1+b1) -> relu(·W2+b2), scatter to hout[recv]
// 64 edges/block, 256 threads (4 waves). mfma_f32_16x16x32_bf16.
template<int HD>
__global__ __launch_bounds__(256) void msg_mfma_k(
    const void* __restrict__ hin,            // HD=6: const float* x; HD=128: const ushort* h1b
    const float* __restrict__ e8,
    const int* __restrict__ cse, const int* __restrict__ cre,
    const int* __restrict__ ecnt,
    const unsigned short* __restrict__ w1s, const float* __restrict__ b1,  // packed [KT1][16][64][8]
    const unsigned short* __restrict__ w2s, const float* __restrict__ b2,  // packed [8][8][64][8]
    float* __restrict__ hout)                                              // [NN,128] zeroed
{
    constexpr int KIN = 2 * HD + 7;                 // 19 or 263
    constexpr int KT1 = (KIN + 31) / 32;            // 1 or 9
    constexpr int K1S = KT1 * 32 + 8;               // LDS stride: 40 or 296 (x2B is 16B-aligned)
    __shared__ unsigned short s_a[64][K1S];
    __shared__ unsigned short s_t[64][264];
    __shared__ int s_recv[64];

    const int Ec = *ecnt;
    const int e0 = blockIdx.x * 64;
    if (e0 >= Ec) return;
    const int tid = threadIdx.x;

    // ---- stage A ----
    if constexpr (HD == 128) {
        const unsigned short* hb = (const unsigned short*)hin;
        const int eg = tid >> 2, p = tid & 3;       // 4 threads per edge
        const int e = e0 + eg;
        const bool ev = e < Ec;
        int s = 0, r = 0;
        if (ev) { s = cse[e]; r = cre[e]; }
        if (p == 0) s_recv[eg] = r;
        const unsigned short* src = (p < 2) ? (hb + (size_t)r * 128 + p * 64)
                                            : (hb + (size_t)s * 128 + (p - 2) * 64);
        #pragma unroll
        for (int i = 0; i < 8; ++i) {
            ushort8 v = ushort8(0);
            if (ev) v = *(const ushort8*)(src + i * 8);
            *(ushort8*)&s_a[eg][p * 64 + i * 8] = v;
        }
        *(ushort8*)&s_a[eg][264 + p * 8] = ushort8(0);      // zero pad 264..295
        if (p == 0) {                                        // e-features cols 256..263
            ushort8 v = ushort8(0);
            if (ev) {
                const float4 ea = *(const float4*)&e8[(size_t)e * 8];
                const float4 eb = *(const float4*)&e8[(size_t)e * 8 + 4];
                v[0] = f2b(ea.x); v[1] = f2b(ea.y); v[2] = f2b(ea.z); v[3] = f2b(ea.w);
                v[4] = f2b(eb.x); v[5] = f2b(eb.y); v[6] = f2b(eb.z); v[7] = 0;
            }
            *(ushort8*)&s_a[eg][256] = v;
        }
    } else {
        if (tid < 64) {
            const float* xf = (const float*)hin;
            const int e = e0 + tid;
            const bool ev = e < Ec;
            int s = 0, r = 0;
            if (ev) { s = cse[e]; r = cre[e]; }
            s_recv[tid] = r;
            float a[19];
            #pragma unroll
            for (int c = 0; c < 19; ++c) a[c] = 0.f;
            if (ev) {
                const float* xr = xf + (size_t)r * 6;
                const float* xs = xf + (size_t)s * 6;
                #pragma unroll
                for (int c = 0; c < 6; ++c) { a[c] = xr[c]; a[6 + c] = xs[c]; }
                #pragma unroll
                for (int c = 0; c < 7; ++c) a[12 + c] = e8[(size_t)e * 8 + c];
            }
            unsigned short u[40];
            #pragma unroll
            for (int c = 0; c < 19; ++c) u[c] = f2b(a[c]);
            #pragma unroll
            for (int c = 19; c < 40; ++c) u[c] = 0;
            #pragma unroll
            for (int c = 0; c < 5; ++c)
                *(ushort8*)&s_a[tid][c * 8] = *(ushort8*)&u[c * 8];
        }
    }
    __syncthreads();

    const int wv  = tid >> 6;        // wave 0..3
    const int lane = tid & 63;
    const int lhi = lane >> 4, llo = lane & 15;
    const short8* w1f = (const short8*)w1s;
    const short8* w2f = (const short8*)w2s;

    // ---- layer 1: [64,KIN] x [KIN,256]; wave wv owns cols wv*64..wv*64+63 ----
    {
        f32x4 acc[4][4];                              // [q(ntile)][mt(rowtile)]
        #pragma unroll
        for (int q = 0; q < 4; ++q) {
            const float bv = b1[(wv * 4 + q) * 16 + llo];
            #pragma unroll
            for (int mt = 0; mt < 4; ++mt) acc[q][mt] = f32x4{bv, bv, bv, bv};
        }
        #pragma unroll
        for (int kt = 0; kt < KT1; ++kt) {
            short8 af[4];
            #pragma unroll
            for (int mt = 0; mt < 4; ++mt)
                af[mt] = *(const short8*)&s_a[mt * 16 + llo][kt * 32 + lhi * 8];
            #pragma unroll
            for (int q = 0; q < 4; ++q) {
                const short8 bf = w1f[(kt * 16 + wv * 4 + q) * 64 + lane];
                #pragma unroll
                for (int mt = 0; mt < 4; ++mt)
                    acc[q][mt] = __builtin_amdgcn_mfma_f32_16x16x32_bf16(af[mt], bf, acc[q][mt], 0, 0, 0);
            }
        }
        // relu -> bf16 -> s_t
        #pragma unroll
        for (int q = 0; q < 4; ++q)
            #pragma unroll
            for (int mt = 0; mt < 4; ++mt)
                #pragma unroll
                for (int r = 0; r < 4; ++r)
                    s_t[mt * 16 + lhi * 4 + r][(wv * 4 + q) * 16 + llo] =
                        f2b(fmaxf(acc[q][mt][r], 0.f));
    }
    __syncthreads();

    // ---- layer 2: [64,256] x [256,128]; wave wv owns cols wv*32..wv*32+31 ----
    {
        f32x4 acc[2][4];
        #pragma unroll
        for (int q = 0; q < 2; ++q) {
            const float bv = b2[(wv * 2 + q) * 16 + llo];
            #pragma unroll
            for (int mt = 0; mt < 4; ++mt) acc[q][mt] = f32x4{bv, bv, bv, bv};
        }
        #pragma unroll
        for (int kt = 0; kt < 8; ++kt) {
            short8 af[4];
            #pragma unroll
            for (int mt = 0; mt < 4; ++mt)
                af[mt] = *(const short8*)&s_t[mt * 16 + llo][kt * 32 + lhi * 8];
            #pragma unroll
            for (int q = 0; q < 2; ++q) {
                const short8 bf = w2f[(kt * 8 + wv * 2 + q) * 64 + lane];
                #pragma unroll
                for (int mt = 0; mt < 4; ++mt)
                    acc[q][mt] = __builtin_amdgcn_mfma_f32_16x16x32_bf16(af[mt], bf, acc[q][mt], 0, 0, 0);
            }
        }
        // relu -> atomic scatter
        #pragma unroll
        for (int q = 0; q < 2; ++q)
            #pragma unroll
            for (int mt = 0; mt < 4; ++mt)
                #pragma unroll
                for (int r = 0; r < 4; ++r) {
                    const int m = mt * 16 + lhi * 4 + r;
                    if (e0 + m < Ec) {
                        const float v = fmaxf(acc[q][mt][r], 0.f);
                        unsafeAtomicAdd(&hout[(size_t)s_recv[m] * 128 + (wv * 2 + q) * 16 + llo], v);
                    }
                }
    }
}

// ---------------- node update MLP: 128 -> 128 -> 64 ----------------
__global__ __launch_bounds__(256) void upd_k(
    const float* __restrict__ hin,                                 // [NN,128]
    const float* __restrict__ w1, const float* __restrict__ b1,    // [128,128]
    const float* __restrict__ w2, const float* __restrict__ b2,    // [128,64]
    float* __restrict__ hout)                                      // [NN,64]
{
    __shared__ float s_in[32][132];
    __shared__ float s_t[32][132];
    const int tid = threadIdx.x;
    const int n0 = blockIdx.x * 32;
    {
        const int ng = tid >> 3, sub = tid & 7;
        const float* hr = hin + (size_t)(n0 + ng) * 128;
        #pragma unroll
        for (int c = sub * 4; c < 128; c += 32)
            *(float4*)&s_in[ng][c] = *(const float4*)&hr[c];
    }
    __syncthreads();
    {
        const int j0 = (tid & 31) * 4;
        const int r0 = (tid >> 5) * 4;
        float acc[4][4];
        #pragma unroll
        for (int c = 0; c < 4; ++c) {
            const float bv = b1[j0 + c];
            #pragma unroll
            for (int r = 0; r < 4; ++r) acc[r][c] = bv;
        }
        for (int k0 = 0; k0 < 128; k0 += 4) {
            float4 a[4];
            #pragma unroll
            for (int r = 0; r < 4; ++r) a[r] = *(const float4*)&s_in[r0 + r][k0];
            #pragma unroll
            for (int kk = 0; kk < 4; ++kk) {
                const float4 w = *(const float4*)&w1[(size_t)(k0 + kk) * 128 + j0];
                #pragma unroll
                for (int r = 0; r < 4; ++r) {
                    const float ar = f4c(a[r], kk);
                    acc[r][0] += ar * w.x; acc[r][1] += ar * w.y;
                    acc[r][2] += ar * w.z; acc[r][3] += ar * w.w;
                }
            }
        }
        #pragma unroll
        for (int r = 0; r < 4; ++r)
            *(float4*)&s_t[r0 + r][j0] = make_float4(fmaxf(acc[r][0], 0.f), fmaxf(acc[r][1], 0.f),
                                                     fmaxf(acc[r][2], 0.f), fmaxf(acc[r][3], 0.f));
    }
    __syncthreads();
    {
        const int j0 = (tid & 15) * 4;
        const int r0 = (tid >> 4) * 2;
        float acc[2][4];
        #pragma unroll
        for (int c = 0; c < 4; ++c) {
            const float bv = b2[j0 + c];
            acc[0][c] = bv; acc[1][c] = bv;
        }
        for (int k0 = 0; k0 < 128; k0 += 4) {
            float4 t0 = *(const float4*)&s_t[r0][k0];
            float4 t1 = *(const float4*)&s_t[r0 + 1][k0];
            #pragma unroll
            for (int kk = 0; kk < 4; ++kk) {
                const float4 w = *(const float4*)&w2[(size_t)(k0 + kk) * 64 + j0];
                const float a0 = f4c(t0, kk), a1 = f4c(t1, kk);
                acc[0][0] += a0 * w.x; acc[0][1] += a0 * w.y; acc[0][2] += a0 * w.z; acc[0][3] += a0 * w.w;
                acc[1][0] += a1 * w.x; acc[1][1] += a1 * w.y; acc[1][2] += a1 * w.z; acc[1][3] += a1 * w.w;
            }
        }
        #pragma unroll
        for (int r = 0; r < 2; ++r)
            *(float4*)&hout[(size_t)(n0 + r0 + r) * 64 + j0] =
                make_float4(fmaxf(acc[r][0], 0.f), fmaxf(acc[r][1], 0.f),
                            fmaxf(acc[r][2], 0.f), fmaxf(acc[r][3], 0.f));
    }
}

// ---------------- SAGE neighbor scatter ----------------
__global__ __launch_bounds__(256) void sage_scatter_k(
    const float* __restrict__ h, const int* __restrict__ cse, const int* __restrict__ cre,
    const int* __restrict__ ecnt, float* __restrict__ nbr, float* __restrict__ cnt)
{
    const int gid = blockIdx.x * 256 + threadIdx.x;
    const int e = gid >> 4, c0 = (gid & 15) * 4;
    if (e >= *ecnt) return;
    const int s = cse[e], r = cre[e];
    const float4 hv = *(const float4*)&h[(size_t)s * 64 + c0];
    float* dst = nbr + (size_t)r * 64 + c0;
    unsafeAtomicAdd(dst + 0, hv.x); unsafeAtomicAdd(dst + 1, hv.y);
    unsafeAtomicAdd(dst + 2, hv.z); unsafeAtomicAdd(dst + 3, hv.w);
    if (c0 == 0) unsafeAtomicAdd(cnt + r, 1.f);
}

// ---------------- SAGE node transform + l2norm + relu, fused graph pooling ----------------
__global__ __launch_bounds__(256) void sage_node_k(
    const float* __restrict__ h, const float* __restrict__ nbr, const float* __restrict__ cnt,
    const int* __restrict__ seg,
    const float* __restrict__ sw, const float* __restrict__ sb,
    float* __restrict__ pmax, float* __restrict__ psum, float* __restrict__ npn)
{
    __shared__ float s_in[16][132];
    __shared__ float s_t[16][132];
    __shared__ float s_inv[16];
    __shared__ int   s_seg[16];
    const int tid = threadIdx.x;
    const int n0 = blockIdx.x * 16;
    {
        const int ng = tid >> 4, sub = tid & 15;
        const int n = n0 + ng;
        const int c = sub * 4;
        *(float4*)&s_in[ng][c] = *(const float4*)&h[(size_t)n * 64 + c];
        const float inv = 1.f / fmaxf(cnt[n], 1.f);
        const float4 nb = *(const float4*)&nbr[(size_t)n * 64 + c];
        s_in[ng][64 + c + 0] = nb.x * inv; s_in[ng][64 + c + 1] = nb.y * inv;
        s_in[ng][64 + c + 2] = nb.z * inv; s_in[ng][64 + c + 3] = nb.w * inv;
        if (sub == 0) s_seg[ng] = seg[n];
    }
    __syncthreads();
    {
        const int j = tid & 127;
        const int r0 = (tid >> 7) * 8;
        float acc[8];
        const float bv = sb[j];
        #pragma unroll
        for (int r = 0; r < 8; ++r) acc[r] = bv;
        for (int k0 = 0; k0 < 128; k0 += 4) {
            float4 a[8];
            #pragma unroll
            for (int r = 0; r < 8; ++r) a[r] = *(const float4*)&s_in[r0 + r][k0];
            #pragma unroll
            for (int kk = 0; kk < 4; ++kk) {
                const float w = sw[(size_t)(k0 + kk) * 128 + j];
                #pragma unroll
                for (int r = 0; r < 8; ++r) acc[r] += f4c(a[r], kk) * w;
            }
        }
        #pragma unroll
        for (int r = 0; r < 8; ++r) s_t[r0 + r][j] = acc[r];
    }
    __syncthreads();
    if (tid < 16) {
        float ss = 0.f;
        for (int j = 0; j < 128; ++j) { const float v = s_t[tid][j]; ss += v * v; }
        s_inv[tid] = 1.f / sqrtf(fmaxf(ss, 1e-12f));
    }
    __syncthreads();
    {
        const int j = tid & 127;
        const int r0 = (tid >> 7) * 8;
        #pragma unroll
        for (int r = 0; r < 8; ++r) {
            const int n = r0 + r;
            const float g = fmaxf(s_t[n][j] * s_inv[n], 0.f);
            const int sg = s_seg[n];
            unsafeAtomicAdd(&psum[(size_t)sg * 128 + j], g);
            atomicMax((unsigned int*)&pmax[(size_t)sg * 128 + j], __float_as_uint(g));
        }
    }
    if (tid < 16) unsafeAtomicAdd(&npn[s_seg[tid]], 1.f);
}

// ---------------- decoder + heads ----------------
__global__ __launch_bounds__(256) void dec_heads_k(
    const float* __restrict__ pmax, const float* __restrict__ psum, const float* __restrict__ npn,
    const float* __restrict__ d0w, const float* __restrict__ d0b,
    const float* __restrict__ g0, const float* __restrict__ be0,
    const float* __restrict__ m0, const float* __restrict__ v0,
    const float* __restrict__ d1w, const float* __restrict__ d1b,
    const float* __restrict__ g1, const float* __restrict__ be1,
    const float* __restrict__ m1, const float* __restrict__ v1,
    const float* __restrict__ lw0, const float* __restrict__ lb0,
    const float* __restrict__ lw1, const float* __restrict__ lb1,
    const float* __restrict__ lwo, const float* __restrict__ lbo,
    const float* __restrict__ aw0, const float* __restrict__ ab0,
    const float* __restrict__ aw1, const float* __restrict__ ab1,
    const float* __restrict__ awo, const float* __restrict__ abo,
    const float* __restrict__ sw0, const float* __restrict__ sb0,
    const float* __restrict__ sw1, const float* __restrict__ sb1,
    const float* __restrict__ swo, const float* __restrict__ sbo,
    const float* __restrict__ ascw, const float* __restrict__ ascb,
    float* __restrict__ out)
{
    __shared__ float z0[384];
    __shared__ float z1[1024];
    __shared__ float z2[512];
    __shared__ float ha[192];
    __shared__ float hb[192];
    __shared__ float fin[8];
    const int b = blockIdx.x, tid = threadIdx.x;
    if (tid < 128) {
        const float pm = pmax[(size_t)b * 128 + tid];
        const float ps = psum[(size_t)b * 128 + tid];
        const float nv = fmaxf(npn[b], 1.f);
        z0[tid] = pm; z0[128 + tid] = ps / nv; z0[256 + tid] = ps;
    }
    __syncthreads();
    {
        float acc[4] = { d0b[tid], d0b[tid + 256], d0b[tid + 512], d0b[tid + 768] };
        for (int k = 0; k < 384; ++k) {
            const float zk = z0[k];
            const float* wr = d0w + (size_t)k * 1024 + tid;
            acc[0] += zk * wr[0]; acc[1] += zk * wr[256]; acc[2] += zk * wr[512]; acc[3] += zk * wr[768];
        }
        #pragma unroll
        for (int i = 0; i < 4; ++i) {
            const int j = tid + 256 * i;
            float v = acc[i] > 0.f ? acc[i] : 0.15f * acc[i];
            v = (v - m0[j]) * (1.f / sqrtf(v0[j] + 1e-3f)) * g0[j] + be0[j];
            z1[j] = v;
        }
    }
    __syncthreads();
    {
        float acc[2] = { d1b[tid], d1b[tid + 256] };
        for (int k = 0; k < 1024; ++k) {
            const float zk = z1[k];
            const float* wr = d1w + (size_t)k * 512 + tid;
            acc[0] += zk * wr[0]; acc[1] += zk * wr[256];
        }
        #pragma unroll
        for (int i = 0; i < 2; ++i) {
            const int j = tid + 256 * i;
            float v = acc[i] > 0.f ? acc[i] : 0.15f * acc[i];
            v = (v - m1[j]) * (1.f / sqrtf(v1[j] + 1e-3f)) * g1[j] + be1[j];
            z2[j] = v;
        }
    }
    __syncthreads();
    if (tid < 192) {
        const int hd = tid >> 6, j = tid & 63;
        const float* w0 = hd == 0 ? lw0 : (hd == 1 ? aw0 : sw0);
        const float* b0 = hd == 0 ? lb0 : (hd == 1 ? ab0 : sb0);
        float acc = b0[j];
        for (int k = 0; k < 512; ++k) acc += z2[k] * w0[(size_t)k * 64 + j];
        ha[tid] = acc;
    }
    __syncthreads();
    if (tid < 192) {
        const int hd = tid >> 6, j = tid & 63;
        const float* w1p = hd == 0 ? lw1 : (hd == 1 ? aw1 : sw1);
        const float* b1p = hd == 0 ? lb1 : (hd == 1 ? ab1 : sb1);
        const float* src = &ha[hd * 64];
        float acc = b1p[j];
        for (int k = 0; k < 64; ++k) acc += src[k] * w1p[(size_t)k * 64 + j];
        hb[tid] = acc;
    }
    __syncthreads();
    if (tid < 5) {
        float acc;
        if (tid == 0) { acc = lbo[0]; for (int k = 0; k < 64; ++k) acc += hb[k] * lwo[k]; }
        else if (tid < 3) { const int c = tid - 1; acc = abo[c]; for (int k = 0; k < 64; ++k) acc += hb[64 + k] * awo[k * 2 + c]; }
        else { const int c = tid - 3; acc = sbo[c]; for (int k = 0; k < 64; ++k) acc += hb[128 + k] * swo[k * 2 + c]; }
        fin[tid] = acc;
    }
    __syncthreads();
    if (tid == 0) {
        const float a0 = fin[1], a1 = fin[2];
        const float q0 = a0 * ascw[0] + a1 * ascw[2] + ascb[0];
        const float q1 = a0 * ascw[1] + a1 * ascw[3] + ascb[1];
        const float zen = 1.f / (1.f + expf(-q0));
        const float azi = 1.f / (1.f + expf(-q1));
        const float PI = 3.14159265358979323846f;
        float* o = out + (size_t)b * 5;
        o[0] = fin[0];
        o[1] = zen * PI;
        o[2] = azi * 2.f * PI;
        o[3] = fabsf(fin[3]) + 1e-5f;
        o[4] = fabsf(fin[4]) + 1e-5f;
    }
}

extern "C" void kernel_launch(void* const* d_in, const int* in_sizes, int n_in,
                              void* d_out, int out_size, void* d_ws, size_t ws_size,
                              hipStream_t stream)
{
    const float* x    = (const float*)d_in[0];
    const int* send   = (const int*)d_in[1];
    const int* recv   = (const int*)d_in[2];
    const int* seg    = (const int*)d_in[3];
    const float* m0w1 = (const float*)d_in[4];
    const float* m0b1 = (const float*)d_in[5];
    const float* m0w2 = (const float*)d_in[6];
    const float* m0b2 = (const float*)d_in[7];
    const float* m1w1 = (const float*)d_in[8];
    const float* m1b1 = (const float*)d_in[9];
    const float* m1w2 = (const float*)d_in[10];
    const float* m1b2 = (const float*)d_in[11];
    const float* uw1  = (const float*)d_in[12];
    const float* ub1  = (const float*)d_in[13];
    const float* uw2  = (const float*)d_in[14];
    const float* ub2  = (const float*)d_in[15];
    const float* sgw  = (const float*)d_in[16];
    const float* sgb  = (const float*)d_in[17];
    const float* d0w  = (const float*)d_in[18];
    const float* d0b  = (const float*)d_in[19];
    const float* bn0g = (const float*)d_in[20];
    const float* bn0b = (const float*)d_in[21];
    const float* bn0m = (const float*)d_in[22];
    const float* bn0v = (const float*)d_in[23];
    const float* d1w  = (const float*)d_in[24];
    const float* d1b  = (const float*)d_in[25];
    const float* bn1g = (const float*)d_in[26];
    const float* bn1b = (const float*)d_in[27];
    const float* bn1m = (const float*)d_in[28];
    const float* bn1v = (const float*)d_in[29];
    const float* lw0  = (const float*)d_in[30];
    const float* lb0  = (const float*)d_in[31];
    const float* lw1  = (const float*)d_in[32];
    const float* lb1  = (const float*)d_in[33];
    const float* lwo  = (const float*)d_in[34];
    const float* lbo  = (const float*)d_in[35];
    const float* aw0  = (const float*)d_in[36];
    const float* ab0  = (const float*)d_in[37];
    const float* aw1  = (const float*)d_in[38];
    const float* ab1  = (const float*)d_in[39];
    const float* awo  = (const float*)d_in[40];
    const float* abo  = (const float*)d_in[41];
    const float* sw0  = (const float*)d_in[42];
    const float* sb0  = (const float*)d_in[43];
    const float* sw1  = (const float*)d_in[44];
    const float* sb1  = (const float*)d_in[45];
    const float* swo  = (const float*)d_in[46];
    const float* sbo  = (const float*)d_in[47];
    const float* ascw = (const float*)d_in[48];
    const float* ascb = (const float*)d_in[49];

    char* ws = (char*)d_ws;
    size_t off = 0;
    auto alloc = [&](size_t bytes) { void* p = ws + off; off = (off + bytes + 31) & ~(size_t)31; return p; };
    float* e8   = (float*)alloc((size_t)NE * 8 * 4);
    float* h1   = (float*)alloc((size_t)NN * 128 * 4);
    float* h2   = (float*)alloc((size_t)NN * 128 * 4);
    float* pmax = (float*)alloc((size_t)NB * 128 * 4);   // pmax|psum|npn must stay contiguous
    float* psum = (float*)alloc((size_t)NB * 128 * 4);
    float* npn  = (float*)alloc((size_t)NB * 4);
    int* cse    = (int*)alloc((size_t)NE * 4);
    int* cre    = (int*)alloc((size_t)NE * 4);
    int* ecnt   = (int*)alloc(4);
    unsigned short* h1b  = (unsigned short*)alloc((size_t)NN * 128 * 2);
    unsigned short* w1s0 = (unsigned short*)alloc((size_t)1 * 16 * 512 * 2);
    unsigned short* w2s0 = (unsigned short*)alloc((size_t)8 * 8 * 512 * 2);
    unsigned short* w1s1 = (unsigned short*)alloc((size_t)9 * 16 * 512 * 2);
    unsigned short* w2s1 = (unsigned short*)alloc((size_t)8 * 8 * 512 * 2);
    float* hu   = h1;                                   // [N,64]  (h1 dead after msg1)
    float* nbr  = h2;                                   // [N,64]  (h2 dead after upd)
    float* cnt  = h2 + (size_t)NN * 64;                 // [N]

    // zero accumulators (h1,h2,pmax,psum,npn are contiguous) + edge counter
    hipMemsetAsync(h1, 0, ((size_t)NN * 256 + (size_t)NB * 257) * sizeof(float), stream);
    hipMemsetAsync(ecnt, 0, sizeof(int), stream);

    // pack weights into MFMA fragment order (bf16)
    pack_w_k<<<(1 * 16 * 512 + 255) / 256, 256, 0, stream>>>(m0w1, w1s0, 19, 16, 1, 256);
    pack_w_k<<<(8 * 8 * 512 + 255) / 256, 256, 0, stream>>>(m0w2, w2s0, 256, 8, 8, 128);
    pack_w_k<<<(9 * 16 * 512 + 255) / 256, 256, 0, stream>>>(m1w1, w1s1, 263, 16, 9, 256);
    pack_w_k<<<(8 * 8 * 512 + 255) / 256, 256, 0, stream>>>(m1w2, w2s1, 256, 8, 8, 128);

    edge_compact_k<<<(NE + 255) / 256, 256, 0, stream>>>(x, send, recv, e8, cse, cre, ecnt);
    msg_mfma_k<6><<<NE / 64, 256, 0, stream>>>(x, e8, cse, cre, ecnt, w1s0, m0b1, w2s0, m0b2, h1);
    f2b_k<<<(NN * 128 / 8 + 255) / 256, 256, 0, stream>>>(h1, h1b, NN * 128 / 8);
    msg_mfma_k<128><<<NE / 64, 256, 0, stream>>>(h1b, e8, cse, cre, ecnt, w1s1, m1b1, w2s1, m1b2, h2);
    upd_k<<<NN / 32, 256, 0, stream>>>(h2, uw1, ub1, uw2, ub2, hu);
    hipMemsetAsync(nbr, 0, (size_t)NN * 65 * sizeof(float), stream);
    sage_scatter_k<<<NE * 16 / 256, 256, 0, stream>>>(hu, cse, cre, ecnt, nbr, cnt);
    sage_node_k<<<NN / 16, 256, 0, stream>>>(hu, nbr, cnt, seg, sgw, sgb, pmax, psum, npn);
    dec_heads_k<<<NB, 256, 0, stream>>>(pmax, psum, npn,
        d0w, d0b, bn0g, bn0b, bn0m, bn0v,
        d1w, d1b, bn1g, bn1b, bn1m, bn1v,
        lw0, lb0, lw1, lb1, lwo, lbo,
        aw0, ab0, aw1, ab1, awo, abo,
        sw0, sb0, sw1, sb1, swo, sbo,
        ascw, ascb, (float*)d_out);
}

// Round 3
// 657.453 us; speedup vs baseline: 3.3776x; 1.8102x over previous
//
#include <hip/hip_runtime.h>
#include <hip/hip_bf16.h>
#include <math.h>

constexpr int NN = 60000;   // nodes
constexpr int NE = 480000;  // edges
constexpr int NB = 128;     // graphs
constexpr int NSB = (NN + 255) / 256;   // scan blocks = 235

typedef __attribute__((ext_vector_type(8))) short  short8;
typedef __attribute__((ext_vector_type(8))) unsigned short ushort8;
typedef __attribute__((ext_vector_type(4))) float  f32x4;

__device__ __forceinline__ unsigned short f2b(float x) {
    __hip_bfloat16 h = __float2bfloat16(x);   // RNE
    return *reinterpret_cast<unsigned short*>(&h);
}
__device__ __forceinline__ float f4c(const float4 v, int k) {
    return k == 0 ? v.x : (k == 1 ? v.y : (k == 2 ? v.z : v.w));
}

// ---------------- edge features + forward-in-time compaction + deg histogram ----------------
__global__ __launch_bounds__(256) void edge_compact_k(
    const float* __restrict__ x, const int* __restrict__ send, const int* __restrict__ recv,
    float* __restrict__ e8, int* __restrict__ cse, int* __restrict__ cre, int* __restrict__ ecnt,
    int* __restrict__ deg)
{
    int e = blockIdx.x * 256 + threadIdx.x;
    if (e >= NE) return;
    int s = send[e], r = recv[e];
    const float* xs = x + (size_t)s * 6;
    const float* xr = x + (size_t)r * 6;
    float xs3 = xs[3], xr3 = xr[3];
    if (!(xs3 <= xr3)) return;                 // masked edge contributes nothing anywhere
    float d0 = xr[0] - xs[0], d1 = xr[1] - xs[1], d2 = xr[2] - xs[2];
    float d3 = xr3 - xs3,     d4 = xr[4] - xs[4], d5 = xr[5] - xs[5];
    float dist = sqrtf(d0 * d0 + d1 * d1 + d2 * d2);
    float inv = dist > 0.f ? 1.f / dist : 0.f;
    int slot = atomicAdd(ecnt, 1);
    float4* o = (float4*)(e8 + (size_t)slot * 8);
    o[0] = make_float4(d3, d4, d5, dist);
    o[1] = make_float4(d0 * inv, d1 * inv, d2 * inv, 0.f);
    cse[slot] = s;
    cre[slot] = r;
    atomicAdd(&deg[r], 1);
}

// ---------------- exclusive scan of deg -> rowptr (3 kernels) ----------------
__global__ __launch_bounds__(256) void scan_block_k(const int* __restrict__ deg,
    int* __restrict__ rowptr, int* __restrict__ bsum)
{
    __shared__ int s[256];
    const int tid = threadIdx.x;
    const int i = blockIdx.x * 256 + tid;
    const int v = (i < NN) ? deg[i] : 0;
    s[tid] = v;
    __syncthreads();
    for (int off = 1; off < 256; off <<= 1) {
        int t = (tid >= off) ? s[tid - off] : 0;
        __syncthreads();
        s[tid] += t;
        __syncthreads();
    }
    if (i < NN) rowptr[i] = s[tid] - v;        // block-local exclusive
    if (tid == 255) bsum[blockIdx.x] = s[255];
}

__global__ __launch_bounds__(256) void scan_top_k(int* __restrict__ bsum, int* __restrict__ boff)
{
    __shared__ int s[256];
    const int tid = threadIdx.x;
    const int v = (tid < NSB) ? bsum[tid] : 0;
    s[tid] = v;
    __syncthreads();
    for (int off = 1; off < 256; off <<= 1) {
        int t = (tid >= off) ? s[tid - off] : 0;
        __syncthreads();
        s[tid] += t;
        __syncthreads();
    }
    boff[tid] = s[tid] - v;                    // exclusive
}

__global__ __launch_bounds__(256) void scan_add_k(int* __restrict__ rowptr,
    const int* __restrict__ boff, int* __restrict__ cursor, const int* __restrict__ ecnt)
{
    const int i = blockIdx.x * 256 + threadIdx.x;
    if (i < NN) {
        const int r = rowptr[i] + boff[blockIdx.x];
        rowptr[i] = r;
        cursor[i] = r;
    }
    if (i == 0) rowptr[NN] = *ecnt;
}

// ---------------- fill CSR: edges sorted by recv ----------------
__global__ __launch_bounds__(256) void csr_fill_k(
    const int* __restrict__ cse, const int* __restrict__ cre, const int* __restrict__ ecnt,
    const float* __restrict__ e8, int* __restrict__ cursor,
    int* __restrict__ csr_s, int* __restrict__ csr_r, float* __restrict__ e8c)
{
    const int i = blockIdx.x * 256 + threadIdx.x;
    if (i >= *ecnt) return;
    const int r = cre[i];
    const int pos = atomicAdd(&cursor[r], 1);
    csr_s[pos] = cse[i];
    csr_r[pos] = r;
    const float4* src = (const float4*)&e8[(size_t)i * 8];
    float4* dst = (float4*)&e8c[(size_t)pos * 8];
    dst[0] = src[0]; dst[1] = src[1];
}

// ---------------- pack weights into MFMA B-fragment order ----------------
__global__ __launch_bounds__(256) void pack_w_k(
    const float* __restrict__ w, unsigned short* __restrict__ out,
    int KIN, int NT, int KT, int NCOL)
{
    int idx = blockIdx.x * 256 + threadIdx.x;
    int total = KT * NT * 512;
    if (idx >= total) return;
    int i = idx & 7;
    int lane = (idx >> 3) & 63;
    int t = idx >> 9;            // kt*NT + nt
    int nt = t % NT, kt = t / NT;
    int k = kt * 32 + (lane >> 4) * 8 + i;
    int n = nt * 16 + (lane & 15);
    out[idx] = (k < KIN) ? f2b(w[(size_t)k * NCOL + n]) : (unsigned short)0;
}

// ---------------- fp32 -> bf16 bulk convert ----------------
__global__ __launch_bounds__(256) void f2b_k(const float* __restrict__ in,
                                             unsigned short* __restrict__ out, int n8)
{
    int i = blockIdx.x * 256 + threadIdx.x;
    if (i >= n8) return;
    const float4 a = ((const float4*)in)[i * 2];
    const float4 b = ((const float4*)in)[i * 2 + 1];
    ushort8 o;
    o[0] = f2b(a.x); o[1] = f2b(a.y); o[2] = f2b(a.z); o[3] = f2b(a.w);
    o[4] = f2b(b.x); o[5] = f2b(b.y); o[6] = f2b(b.z); o[7] = f2b(b.w);
    ((ushort8*)out)[i] = o;
}

// ---------------- MFMA edge message MLP, CSR-ordered, run-segmented scatter ----------------
// in = [h[recv](HD), h[send](HD), e(7)] -> relu(·W1+b1) -> relu(·W2+b2), += into hout[recv]
template<int HD>
__global__ __launch_bounds__(256) void msg_mfma_k(
    const void* __restrict__ hin,            // HD=6: const float* x; HD=128: const ushort* h1b
    const float* __restrict__ e8c,
    const int* __restrict__ csr_s, const int* __restrict__ csr_r,
    const int* __restrict__ ecnt,
    const unsigned short* __restrict__ w1s, const float* __restrict__ b1,
    const unsigned short* __restrict__ w2s, const float* __restrict__ b2,
    float* __restrict__ hout)                                              // [NN,128] zeroed
{
    constexpr int KIN = 2 * HD + 7;                 // 19 or 263
    constexpr int KT1 = (KIN + 31) / 32;            // 1 or 9
    constexpr int K1S = KT1 * 32 + 8;               // LDS A stride: 40 or 296
    constexpr int ABYTES = 64 * K1S * 2;
    constexpr int TBYTES = 64 * 264 * 2;
    __shared__ char smem[ABYTES + TBYTES];
    auto s_a = (unsigned short (*)[K1S])smem;
    auto s_t = (unsigned short (*)[264])(smem + ABYTES);
    // fp32 scatter buffer overlays: s_a (HD=128, 37888B>=33280) / s_t (HD=6, 33792B>=33280)
    float (*s_f)[130] = (HD == 128) ? (float (*)[130])smem : (float (*)[130])(smem + ABYTES);
    __shared__ int s_recv[64];

    const int Ec = *ecnt;
    const int e0 = blockIdx.x * 64;
    if (e0 >= Ec) return;
    const int tid = threadIdx.x;

    // ---- stage A ----
    if constexpr (HD == 128) {
        const unsigned short* hb = (const unsigned short*)hin;
        const int eg = tid >> 2, p = tid & 3;       // 4 threads per edge
        const int e = e0 + eg;
        const bool ev = e < Ec;
        int s = 0, r = 0;
        if (ev) { s = csr_s[e]; r = csr_r[e]; }
        if (p == 0) s_recv[eg] = r;
        const unsigned short* src = (p < 2) ? (hb + (size_t)r * 128 + p * 64)
                                            : (hb + (size_t)s * 128 + (p - 2) * 64);
        #pragma unroll
        for (int i = 0; i < 8; ++i) {
            ushort8 v = ushort8(0);
            if (ev) v = *(const ushort8*)(src + i * 8);
            *(ushort8*)&s_a[eg][p * 64 + i * 8] = v;
        }
        *(ushort8*)&s_a[eg][264 + p * 8] = ushort8(0);      // zero pad 264..295
        if (p == 0) {                                        // e-features cols 256..263
            ushort8 v = ushort8(0);
            if (ev) {
                const float4 ea = *(const float4*)&e8c[(size_t)e * 8];
                const float4 eb = *(const float4*)&e8c[(size_t)e * 8 + 4];
                v[0] = f2b(ea.x); v[1] = f2b(ea.y); v[2] = f2b(ea.z); v[3] = f2b(ea.w);
                v[4] = f2b(eb.x); v[5] = f2b(eb.y); v[6] = f2b(eb.z); v[7] = 0;
            }
            *(ushort8*)&s_a[eg][256] = v;
        }
    } else {
        if (tid < 64) {
            const float* xf = (const float*)hin;
            const int e = e0 + tid;
            const bool ev = e < Ec;
            int s = 0, r = 0;
            if (ev) { s = csr_s[e]; r = csr_r[e]; }
            s_recv[tid] = r;
            float a[19];
            #pragma unroll
            for (int c = 0; c < 19; ++c) a[c] = 0.f;
            if (ev) {
                const float* xr = xf + (size_t)r * 6;
                const float* xs = xf + (size_t)s * 6;
                #pragma unroll
                for (int c = 0; c < 6; ++c) { a[c] = xr[c]; a[6 + c] = xs[c]; }
                #pragma unroll
                for (int c = 0; c < 7; ++c) a[12 + c] = e8c[(size_t)e * 8 + c];
            }
            unsigned short u[40];
            #pragma unroll
            for (int c = 0; c < 19; ++c) u[c] = f2b(a[c]);
            #pragma unroll
            for (int c = 19; c < 40; ++c) u[c] = 0;
            #pragma unroll
            for (int c = 0; c < 5; ++c)
                *(ushort8*)&s_a[tid][c * 8] = *(ushort8*)&u[c * 8];
        }
    }
    __syncthreads();

    const int wv  = tid >> 6;        // wave 0..3
    const int lane = tid & 63;
    const int lhi = lane >> 4, llo = lane & 15;
    const short8* w1f = (const short8*)w1s;
    const short8* w2f = (const short8*)w2s;

    // ---- layer 1: [64,KIN] x [KIN,256]; wave wv owns cols wv*64..wv*64+63 ----
    {
        f32x4 acc[4][4];                              // [q(ntile)][mt(rowtile)]
        #pragma unroll
        for (int q = 0; q < 4; ++q) {
            const float bv = b1[(wv * 4 + q) * 16 + llo];
            #pragma unroll
            for (int mt = 0; mt < 4; ++mt) acc[q][mt] = f32x4{bv, bv, bv, bv};
        }
        #pragma unroll
        for (int kt = 0; kt < KT1; ++kt) {
            short8 af[4];
            #pragma unroll
            for (int mt = 0; mt < 4; ++mt)
                af[mt] = *(const short8*)&s_a[mt * 16 + llo][kt * 32 + lhi * 8];
            #pragma unroll
            for (int q = 0; q < 4; ++q) {
                const short8 bf = w1f[(kt * 16 + wv * 4 + q) * 64 + lane];
                #pragma unroll
                for (int mt = 0; mt < 4; ++mt)
                    acc[q][mt] = __builtin_amdgcn_mfma_f32_16x16x32_bf16(af[mt], bf, acc[q][mt], 0, 0, 0);
            }
        }
        // relu -> bf16 -> s_t
        #pragma unroll
        for (int q = 0; q < 4; ++q)
            #pragma unroll
            for (int mt = 0; mt < 4; ++mt)
                #pragma unroll
                for (int r = 0; r < 4; ++r)
                    s_t[mt * 16 + lhi * 4 + r][(wv * 4 + q) * 16 + llo] =
                        f2b(fmaxf(acc[q][mt][r], 0.f));
    }
    __syncthreads();

    // ---- layer 2: [64,256] x [256,128]; wave wv owns cols wv*32..wv*32+31 ----
    {
        f32x4 acc[2][4];
        #pragma unroll
        for (int q = 0; q < 2; ++q) {
            const float bv = b2[(wv * 2 + q) * 16 + llo];
            #pragma unroll
            for (int mt = 0; mt < 4; ++mt) acc[q][mt] = f32x4{bv, bv, bv, bv};
        }
        #pragma unroll
        for (int kt = 0; kt < 8; ++kt) {
            short8 af[4];
            #pragma unroll
            for (int mt = 0; mt < 4; ++mt)
                af[mt] = *(const short8*)&s_t[mt * 16 + llo][kt * 32 + lhi * 8];
            #pragma unroll
            for (int q = 0; q < 2; ++q) {
                const short8 bf = w2f[(kt * 8 + wv * 2 + q) * 64 + lane];
                #pragma unroll
                for (int mt = 0; mt < 4; ++mt)
                    acc[q][mt] = __builtin_amdgcn_mfma_f32_16x16x32_bf16(af[mt], bf, acc[q][mt], 0, 0, 0);
            }
        }
        __syncthreads();            // all reads of s_a/s_t complete before overlay write
        #pragma unroll
        for (int q = 0; q < 2; ++q)
            #pragma unroll
            for (int mt = 0; mt < 4; ++mt)
                #pragma unroll
                for (int r = 0; r < 4; ++r)
                    s_f[mt * 16 + lhi * 4 + r][(wv * 2 + q) * 16 + llo] =
                        fmaxf(acc[q][mt][r], 0.f);
    }
    __syncthreads();

    // ---- run-segmented scatter: edges sorted by recv -> one atomic per run ----
    {
        const int c = tid & 127, hf = tid >> 7;
        int cur = -1; float run = 0.f;
        for (int i = 0; i < 32; ++i) {
            const int row = hf * 32 + i;
            if (e0 + row >= Ec) break;
            const int rv = s_recv[row];
            if (rv != cur) {
                if (cur >= 0) unsafeAtomicAdd(&hout[(size_t)cur * 128 + c], run);
                cur = rv; run = 0.f;
            }
            run += s_f[row][c];
        }
        if (cur >= 0) unsafeAtomicAdd(&hout[(size_t)cur * 128 + c], run);
    }
}

// ---------------- node update MLP: 128 -> 128 -> 64 ----------------
__global__ __launch_bounds__(256) void upd_k(
    const float* __restrict__ hin,
    const float* __restrict__ w1, const float* __restrict__ b1,
    const float* __restrict__ w2, const float* __restrict__ b2,
    float* __restrict__ hout)
{
    __shared__ float s_in[32][132];
    __shared__ float s_t[32][132];
    const int tid = threadIdx.x;
    const int n0 = blockIdx.x * 32;
    {
        const int ng = tid >> 3, sub = tid & 7;
        const float* hr = hin + (size_t)(n0 + ng) * 128;
        #pragma unroll
        for (int c = sub * 4; c < 128; c += 32)
            *(float4*)&s_in[ng][c] = *(const float4*)&hr[c];
    }
    __syncthreads();
    {
        const int j0 = (tid & 31) * 4;
        const int r0 = (tid >> 5) * 4;
        float acc[4][4];
        #pragma unroll
        for (int c = 0; c < 4; ++c) {
            const float bv = b1[j0 + c];
            #pragma unroll
            for (int r = 0; r < 4; ++r) acc[r][c] = bv;
        }
        for (int k0 = 0; k0 < 128; k0 += 4) {
            float4 a[4];
            #pragma unroll
            for (int r = 0; r < 4; ++r) a[r] = *(const float4*)&s_in[r0 + r][k0];
            #pragma unroll
            for (int kk = 0; kk < 4; ++kk) {
                const float4 w = *(const float4*)&w1[(size_t)(k0 + kk) * 128 + j0];
                #pragma unroll
                for (int r = 0; r < 4; ++r) {
                    const float ar = f4c(a[r], kk);
                    acc[r][0] += ar * w.x; acc[r][1] += ar * w.y;
                    acc[r][2] += ar * w.z; acc[r][3] += ar * w.w;
                }
            }
        }
        #pragma unroll
        for (int r = 0; r < 4; ++r)
            *(float4*)&s_t[r0 + r][j0] = make_float4(fmaxf(acc[r][0], 0.f), fmaxf(acc[r][1], 0.f),
                                                     fmaxf(acc[r][2], 0.f), fmaxf(acc[r][3], 0.f));
    }
    __syncthreads();
    {
        const int j0 = (tid & 15) * 4;
        const int r0 = (tid >> 4) * 2;
        float acc[2][4];
        #pragma unroll
        for (int c = 0; c < 4; ++c) {
            const float bv = b2[j0 + c];
            acc[0][c] = bv; acc[1][c] = bv;
        }
        for (int k0 = 0; k0 < 128; k0 += 4) {
            float4 t0 = *(const float4*)&s_t[r0][k0];
            float4 t1 = *(const float4*)&s_t[r0 + 1][k0];
            #pragma unroll
            for (int kk = 0; kk < 4; ++kk) {
                const float4 w = *(const float4*)&w2[(size_t)(k0 + kk) * 64 + j0];
                const float a0 = f4c(t0, kk), a1 = f4c(t1, kk);
                acc[0][0] += a0 * w.x; acc[0][1] += a0 * w.y; acc[0][2] += a0 * w.z; acc[0][3] += a0 * w.w;
                acc[1][0] += a1 * w.x; acc[1][1] += a1 * w.y; acc[1][2] += a1 * w.z; acc[1][3] += a1 * w.w;
            }
        }
        #pragma unroll
        for (int r = 0; r < 2; ++r)
            *(float4*)&hout[(size_t)(n0 + r0 + r) * 64 + j0] =
                make_float4(fmaxf(acc[r][0], 0.f), fmaxf(acc[r][1], 0.f),
                            fmaxf(acc[r][2], 0.f), fmaxf(acc[r][3], 0.f));
    }
}

// ---------------- SAGE: inline CSR gather-mean + MFMA transform + l2norm + pooled reduce ----------------
__global__ __launch_bounds__(256) void sage_node_k(
    const float* __restrict__ hu,                       // [NN,64]
    const int* __restrict__ rowptr, const int* __restrict__ csr_s,
    const int* __restrict__ seg,
    const unsigned short* __restrict__ wss, const float* __restrict__ sb,  // packed [4][8][64][8]
    float* __restrict__ pmax, float* __restrict__ psum, float* __restrict__ npn)
{
    __shared__ unsigned short s_in[64][136];
    __shared__ float s_g[64][130];
    __shared__ float s_inv[64];
    __shared__ int   s_seg[64];
    const int tid = threadIdx.x;
    const int n0 = blockIdx.x * 64;

    { // ---- stage: 4 threads/node, 16 cols each; gather neighbor mean from CSR ----
        const int ng = tid >> 2, p = tid & 3;
        const int n = n0 + ng;
        if (n < NN) {
            if (p == 0) s_seg[ng] = seg[n];
            const float* hr = hu + (size_t)n * 64 + p * 16;
            float a[16];
            #pragma unroll
            for (int k = 0; k < 4; ++k) {
                const float4 v = *(const float4*)(hr + k * 4);
                a[k*4] = v.x; a[k*4+1] = v.y; a[k*4+2] = v.z; a[k*4+3] = v.w;
            }
            float s[16];
            #pragma unroll
            for (int k = 0; k < 16; ++k) s[k] = 0.f;
            const int rb = rowptr[n], re = rowptr[n + 1];
            for (int e = rb; e < re; ++e) {
                const float* hs = hu + (size_t)csr_s[e] * 64 + p * 16;
                #pragma unroll
                for (int k = 0; k < 4; ++k) {
                    const float4 v = *(const float4*)(hs + k * 4);
                    s[k*4] += v.x; s[k*4+1] += v.y; s[k*4+2] += v.z; s[k*4+3] += v.w;
                }
            }
            const float inv = (re > rb) ? 1.f / (float)(re - rb) : 0.f;
            unsigned short uh[16], ua[16];
            #pragma unroll
            for (int k = 0; k < 16; ++k) { uh[k] = f2b(a[k]); ua[k] = f2b(s[k] * inv); }
            *(ushort8*)&s_in[ng][p * 16]          = *(ushort8*)&uh[0];
            *(ushort8*)&s_in[ng][p * 16 + 8]      = *(ushort8*)&uh[8];
            *(ushort8*)&s_in[ng][64 + p * 16]     = *(ushort8*)&ua[0];
            *(ushort8*)&s_in[ng][64 + p * 16 + 8] = *(ushort8*)&ua[8];
        } else {
            if (p == 0) s_seg[ng] = -1;
            *(ushort8*)&s_in[ng][p * 16]          = ushort8(0);
            *(ushort8*)&s_in[ng][p * 16 + 8]      = ushort8(0);
            *(ushort8*)&s_in[ng][64 + p * 16]     = ushort8(0);
            *(ushort8*)&s_in[ng][64 + p * 16 + 8] = ushort8(0);
        }
    }
    __syncthreads();

    const int wv = tid >> 6, lane = tid & 63, lhi = lane >> 4, llo = lane & 15;
    const short8* wf = (const short8*)wss;
    { // ---- [64,128] x [128,128] MFMA; wave wv owns cols wv*32..wv*32+31 ----
        f32x4 acc[2][4];
        #pragma unroll
        for (int q = 0; q < 2; ++q) {
            const float bv = sb[(wv * 2 + q) * 16 + llo];
            #pragma unroll
            for (int mt = 0; mt < 4; ++mt) acc[q][mt] = f32x4{bv, bv, bv, bv};
        }
        #pragma unroll
        for (int kt = 0; kt < 4; ++kt) {
            short8 af[4];
            #pragma unroll
            for (int mt = 0; mt < 4; ++mt)
                af[mt] = *(const short8*)&s_in[mt * 16 + llo][kt * 32 + lhi * 8];
            #pragma unroll
            for (int q = 0; q < 2; ++q) {
                const short8 bf = wf[(kt * 8 + wv * 2 + q) * 64 + lane];
                #pragma unroll
                for (int mt = 0; mt < 4; ++mt)
                    acc[q][mt] = __builtin_amdgcn_mfma_f32_16x16x32_bf16(af[mt], bf, acc[q][mt], 0, 0, 0);
            }
        }
        #pragma unroll
        for (int q = 0; q < 2; ++q)
            #pragma unroll
            for (int mt = 0; mt < 4; ++mt)
                #pragma unroll
                for (int r = 0; r < 4; ++r)
                    s_g[mt * 16 + lhi * 4 + r][(wv * 2 + q) * 16 + llo] = acc[q][mt][r];
    }
    __syncthreads();
    { // ---- l2 norm (pre-relu, fp32): 4 threads/row ----
        const int row = tid >> 2, p = tid & 3;
        float ss = 0.f;
        #pragma unroll
        for (int k = 0; k < 32; ++k) { const float v = s_g[row][p * 32 + k]; ss += v * v; }
        ss += __shfl_xor(ss, 1);
        ss += __shfl_xor(ss, 2);
        if (p == 0) s_inv[row] = rsqrtf(fmaxf(ss, 1e-12f));
    }
    __syncthreads();
    { // ---- run-segmented pooling: seg sorted -> one atomic pair per run per col ----
        const int c = tid & 127, hf = tid >> 7;
        int cur = -1; float rs = 0.f, rm = 0.f;     // g >= 0, so 0 is a valid max identity
        for (int i = 0; i < 32; ++i) {
            const int row = hf * 32 + i;
            if (n0 + row >= NN) break;
            const int sg = s_seg[row];
            const float g = fmaxf(s_g[row][c] * s_inv[row], 0.f);
            if (sg != cur) {
                if (cur >= 0) {
                    unsafeAtomicAdd(&psum[(size_t)cur * 128 + c], rs);
                    atomicMax((unsigned int*)&pmax[(size_t)cur * 128 + c], __float_as_uint(rm));
                }
                cur = sg; rs = 0.f; rm = 0.f;
            }
            rs += g; rm = fmaxf(rm, g);
        }
        if (cur >= 0) {
            unsafeAtomicAdd(&psum[(size_t)cur * 128 + c], rs);
            atomicMax((unsigned int*)&pmax[(size_t)cur * 128 + c], __float_as_uint(rm));
        }
    }
    if (tid == 0 || tid == 128) { // ---- npn: node counts per run ----
        const int hf = tid >> 7;
        int cur = -1; float cnt = 0.f;
        for (int i = 0; i < 32; ++i) {
            const int row = hf * 32 + i;
            if (n0 + row >= NN) break;
            const int sg = s_seg[row];
            if (sg != cur) { if (cur >= 0) unsafeAtomicAdd(&npn[cur], cnt); cur = sg; cnt = 0.f; }
            cnt += 1.f;
        }
        if (cur >= 0) unsafeAtomicAdd(&npn[cur], cnt);
    }
}

// ---------------- decoder + heads ----------------
__global__ __launch_bounds__(256) void dec_heads_k(
    const float* __restrict__ pmax, const float* __restrict__ psum, const float* __restrict__ npn,
    const float* __restrict__ d0w, const float* __restrict__ d0b,
    const float* __restrict__ g0, const float* __restrict__ be0,
    const float* __restrict__ m0, const float* __restrict__ v0,
    const float* __restrict__ d1w, const float* __restrict__ d1b,
    const float* __restrict__ g1, const float* __restrict__ be1,
    const float* __restrict__ m1, const float* __restrict__ v1,
    const float* __restrict__ lw0, const float* __restrict__ lb0,
    const float* __restrict__ lw1, const float* __restrict__ lb1,
    const float* __restrict__ lwo, const float* __restrict__ lbo,
    const float* __restrict__ aw0, const float* __restrict__ ab0,
    const float* __restrict__ aw1, const float* __restrict__ ab1,
    const float* __restrict__ awo, const float* __restrict__ abo,
    const float* __restrict__ sw0, const float* __restrict__ sb0,
    const float* __restrict__ sw1, const float* __restrict__ sb1,
    const float* __restrict__ swo, const float* __restrict__ sbo,
    const float* __restrict__ ascw, const float* __restrict__ ascb,
    float* __restrict__ out)
{
    __shared__ float z0[384];
    __shared__ float z1[1024];
    __shared__ float z2[512];
    __shared__ float ha[192];
    __shared__ float hb[192];
    __shared__ float fin[8];
    const int b = blockIdx.x, tid = threadIdx.x;
    if (tid < 128) {
        const float pm = pmax[(size_t)b * 128 + tid];
        const float ps = psum[(size_t)b * 128 + tid];
        const float nv = fmaxf(npn[b], 1.f);
        z0[tid] = pm; z0[128 + tid] = ps / nv; z0[256 + tid] = ps;
    }
    __syncthreads();
    {
        float acc[4] = { d0b[tid], d0b[tid + 256], d0b[tid + 512], d0b[tid + 768] };
        for (int k = 0; k < 384; ++k) {
            const float zk = z0[k];
            const float* wr = d0w + (size_t)k * 1024 + tid;
            acc[0] += zk * wr[0]; acc[1] += zk * wr[256]; acc[2] += zk * wr[512]; acc[3] += zk * wr[768];
        }
        #pragma unroll
        for (int i = 0; i < 4; ++i) {
            const int j = tid + 256 * i;
            float v = acc[i] > 0.f ? acc[i] : 0.15f * acc[i];
            v = (v - m0[j]) * (1.f / sqrtf(v0[j] + 1e-3f)) * g0[j] + be0[j];
            z1[j] = v;
        }
    }
    __syncthreads();
    {
        float acc[2] = { d1b[tid], d1b[tid + 256] };
        for (int k = 0; k < 1024; ++k) {
            const float zk = z1[k];
            const float* wr = d1w + (size_t)k * 512 + tid;
            acc[0] += zk * wr[0]; acc[1] += zk * wr[256];
        }
        #pragma unroll
        for (int i = 0; i < 2; ++i) {
            const int j = tid + 256 * i;
            float v = acc[i] > 0.f ? acc[i] : 0.15f * acc[i];
            v = (v - m1[j]) * (1.f / sqrtf(v1[j] + 1e-3f)) * g1[j] + be1[j];
            z2[j] = v;
        }
    }
    __syncthreads();
    if (tid < 192) {
        const int hd = tid >> 6, j = tid & 63;
        const float* w0 = hd == 0 ? lw0 : (hd == 1 ? aw0 : sw0);
        const float* b0 = hd == 0 ? lb0 : (hd == 1 ? ab0 : sb0);
        float acc = b0[j];
        for (int k = 0; k < 512; ++k) acc += z2[k] * w0[(size_t)k * 64 + j];
        ha[tid] = acc;
    }
    __syncthreads();
    if (tid < 192) {
        const int hd = tid >> 6, j = tid & 63;
        const float* w1p = hd == 0 ? lw1 : (hd == 1 ? aw1 : sw1);
        const float* b1p = hd == 0 ? lb1 : (hd == 1 ? ab1 : sb1);
        const float* src = &ha[hd * 64];
        float acc = b1p[j];
        for (int k = 0; k < 64; ++k) acc += src[k] * w1p[(size_t)k * 64 + j];
        hb[tid] = acc;
    }
    __syncthreads();
    if (tid < 5) {
        float acc;
        if (tid == 0) { acc = lbo[0]; for (int k = 0; k < 64; ++k) acc += hb[k] * lwo[k]; }
        else if (tid < 3) { const int c = tid - 1; acc = abo[c]; for (int k = 0; k < 64; ++k) acc += hb[64 + k] * awo[k * 2 + c]; }
        else { const int c = tid - 3; acc = sbo[c]; for (int k = 0; k < 64; ++k) acc += hb[128 + k] * swo[k * 2 + c]; }
        fin[tid] = acc;
    }
    __syncthreads();
    if (tid == 0) {
        const float a0 = fin[1], a1 = fin[2];
        const float q0 = a0 * ascw[0] + a1 * ascw[2] + ascb[0];
        const float q1 = a0 * ascw[1] + a1 * ascw[3] + ascb[1];
        const float zen = 1.f / (1.f + expf(-q0));
        const float azi = 1.f / (1.f + expf(-q1));
        const float PI = 3.14159265358979323846f;
        float* o = out + (size_t)b * 5;
        o[0] = fin[0];
        o[1] = zen * PI;
        o[2] = azi * 2.f * PI;
        o[3] = fabsf(fin[3]) + 1e-5f;
        o[4] = fabsf(fin[4]) + 1e-5f;
    }
}

extern "C" void kernel_launch(void* const* d_in, const int* in_sizes, int n_in,
                              void* d_out, int out_size, void* d_ws, size_t ws_size,
                              hipStream_t stream)
{
    const float* x    = (const float*)d_in[0];
    const int* send   = (const int*)d_in[1];
    const int* recv   = (const int*)d_in[2];
    const int* seg    = (const int*)d_in[3];
    const float* m0w1 = (const float*)d_in[4];
    const float* m0b1 = (const float*)d_in[5];
    const float* m0w2 = (const float*)d_in[6];
    const float* m0b2 = (const float*)d_in[7];
    const float* m1w1 = (const float*)d_in[8];
    const float* m1b1 = (const float*)d_in[9];
    const float* m1w2 = (const float*)d_in[10];
    const float* m1b2 = (const float*)d_in[11];
    const float* uw1  = (const float*)d_in[12];
    const float* ub1  = (const float*)d_in[13];
    const float* uw2  = (const float*)d_in[14];
    const float* ub2  = (const float*)d_in[15];
    const float* sgw  = (const float*)d_in[16];
    const float* sgb  = (const float*)d_in[17];
    const float* d0w  = (const float*)d_in[18];
    const float* d0b  = (const float*)d_in[19];
    const float* bn0g = (const float*)d_in[20];
    const float* bn0b = (const float*)d_in[21];
    const float* bn0m = (const float*)d_in[22];
    const float* bn0v = (const float*)d_in[23];
    const float* d1w  = (const float*)d_in[24];
    const float* d1b  = (const float*)d_in[25];
    const float* bn1g = (const float*)d_in[26];
    const float* bn1b = (const float*)d_in[27];
    const float* bn1m = (const float*)d_in[28];
    const float* bn1v = (const float*)d_in[29];
    const float* lw0  = (const float*)d_in[30];
    const float* lb0  = (const float*)d_in[31];
    const float* lw1  = (const float*)d_in[32];
    const float* lb1  = (const float*)d_in[33];
    const float* lwo  = (const float*)d_in[34];
    const float* lbo  = (const float*)d_in[35];
    const float* aw0  = (const float*)d_in[36];
    const float* ab0  = (const float*)d_in[37];
    const float* aw1  = (const float*)d_in[38];
    const float* ab1  = (const float*)d_in[39];
    const float* awo  = (const float*)d_in[40];
    const float* abo  = (const float*)d_in[41];
    const float* sw0  = (const float*)d_in[42];
    const float* sb0  = (const float*)d_in[43];
    const float* sw1  = (const float*)d_in[44];
    const float* sb1  = (const float*)d_in[45];
    const float* swo  = (const float*)d_in[46];
    const float* sbo  = (const float*)d_in[47];
    const float* ascw = (const float*)d_in[48];
    const float* ascb = (const float*)d_in[49];

    char* ws = (char*)d_ws;
    size_t off = 0;
    auto alloc = [&](size_t bytes) { void* p = ws + off; off = (off + bytes + 31) & ~(size_t)31; return p; };
    // zero-region: h1,h2,pmax,psum,npn contiguous
    float* h1   = (float*)alloc((size_t)NN * 128 * 4);
    float* h2   = (float*)alloc((size_t)NN * 128 * 4);
    float* pmax = (float*)alloc((size_t)NB * 128 * 4);
    float* psum = (float*)alloc((size_t)NB * 128 * 4);
    float* npn  = (float*)alloc((size_t)NB * 4);
    float* e8   = (float*)alloc((size_t)NE * 8 * 4);
    float* e8c  = (float*)alloc((size_t)NE * 8 * 4);
    int* cse    = (int*)alloc((size_t)NE * 4);
    int* cre    = (int*)alloc((size_t)NE * 4);
    int* csr_s  = (int*)alloc((size_t)NE * 4);
    int* csr_r  = (int*)alloc((size_t)NE * 4);
    int* deg    = (int*)alloc((size_t)NN * 4);
    int* rowptr = (int*)alloc((size_t)(NN + 1) * 4);
    int* cursor = (int*)alloc((size_t)NN * 4);
    int* bsum   = (int*)alloc(256 * 4);
    int* boff   = (int*)alloc(256 * 4);
    int* ecnt   = (int*)alloc(4);
    unsigned short* h1b  = (unsigned short*)alloc((size_t)NN * 128 * 2);
    unsigned short* w1s0 = (unsigned short*)alloc((size_t)1 * 16 * 512 * 2);
    unsigned short* w2s0 = (unsigned short*)alloc((size_t)8 * 8 * 512 * 2);
    unsigned short* w1s1 = (unsigned short*)alloc((size_t)9 * 16 * 512 * 2);
    unsigned short* w2s1 = (unsigned short*)alloc((size_t)8 * 8 * 512 * 2);
    unsigned short* wss  = (unsigned short*)alloc((size_t)4 * 8 * 512 * 2);
    float* hu = h1;                                   // [N,64] (h1 fp32 dead after f2b)

    hipMemsetAsync(h1, 0, ((size_t)NN * 256 + (size_t)NB * 257) * sizeof(float), stream);
    hipMemsetAsync(deg, 0, (size_t)NN * sizeof(int), stream);
    hipMemsetAsync(ecnt, 0, sizeof(int), stream);

    pack_w_k<<<(1 * 16 * 512 + 255) / 256, 256, 0, stream>>>(m0w1, w1s0, 19, 16, 1, 256);
    pack_w_k<<<(8 * 8 * 512 + 255) / 256, 256, 0, stream>>>(m0w2, w2s0, 256, 8, 8, 128);
    pack_w_k<<<(9 * 16 * 512 + 255) / 256, 256, 0, stream>>>(m1w1, w1s1, 263, 16, 9, 256);
    pack_w_k<<<(8 * 8 * 512 + 255) / 256, 256, 0, stream>>>(m1w2, w2s1, 256, 8, 8, 128);
    pack_w_k<<<(4 * 8 * 512 + 255) / 256, 256, 0, stream>>>(sgw, wss, 128, 8, 4, 128);

    edge_compact_k<<<(NE + 255) / 256, 256, 0, stream>>>(x, send, recv, e8, cse, cre, ecnt, deg);
    scan_block_k<<<NSB, 256, 0, stream>>>(deg, rowptr, bsum);
    scan_top_k<<<1, 256, 0, stream>>>(bsum, boff);
    scan_add_k<<<NSB, 256, 0, stream>>>(rowptr, boff, cursor, ecnt);
    csr_fill_k<<<(NE + 255) / 256, 256, 0, stream>>>(cse, cre, ecnt, e8, cursor, csr_s, csr_r, e8c);

    msg_mfma_k<6><<<NE / 64, 256, 0, stream>>>(x, e8c, csr_s, csr_r, ecnt, w1s0, m0b1, w2s0, m0b2, h1);
    f2b_k<<<(NN * 128 / 8 + 255) / 256, 256, 0, stream>>>(h1, h1b, NN * 128 / 8);
    msg_mfma_k<128><<<NE / 64, 256, 0, stream>>>(h1b, e8c, csr_s, csr_r, ecnt, w1s1, m1b1, w2s1, m1b2, h2);
    upd_k<<<NN / 32, 256, 0, stream>>>(h2, uw1, ub1, uw2, ub2, hu);
    sage_node_k<<<(NN + 63) / 64, 256, 0, stream>>>(hu, rowptr, csr_s, seg, wss, sgb, pmax, psum, npn);
    dec_heads_k<<<NB, 256, 0, stream>>>(pmax, psum, npn,
        d0w, d0b, bn0g, bn0b, bn0m, bn0v,
        d1w, d1b, bn1g, bn1b, bn1m, bn1v,
        lw0, lb0, lw1, lb1, lwo, lbo,
        aw0, ab0, aw1, ab1, awo, abo,
        sw0, sb0, sw1, sb1, swo, sbo,
        ascw, ascb, (float*)d_out);
}

// Round 4
// 580.544 us; speedup vs baseline: 3.8251x; 1.1325x over previous
//
#include <hip/hip_runtime.h>
#include <hip/hip_bf16.h>
#include <math.h>

constexpr int NN = 60000;   // nodes
constexpr int NE = 480000;  // edges
constexpr int NB = 128;     // graphs
constexpr int NSB = (NN + 255) / 256;   // scan blocks = 235

typedef __attribute__((ext_vector_type(8))) short  short8;
typedef __attribute__((ext_vector_type(8))) unsigned short ushort8;
typedef __attribute__((ext_vector_type(4))) float  f32x4;

__device__ __forceinline__ unsigned short f2b(float x) {
    __hip_bfloat16 h = __float2bfloat16(x);   // RNE
    return *reinterpret_cast<unsigned short*>(&h);
}
__device__ __forceinline__ float f4c(const float4 v, int k) {
    return k == 0 ? v.x : (k == 1 ? v.y : (k == 2 ? v.z : v.w));
}

// ---------------- edge features + forward-in-time compaction + deg histogram ----------------
__global__ __launch_bounds__(256) void edge_compact_k(
    const float* __restrict__ x, const int* __restrict__ send, const int* __restrict__ recv,
    float* __restrict__ e8, int* __restrict__ cse, int* __restrict__ cre, int* __restrict__ ecnt,
    int* __restrict__ deg)
{
    int e = blockIdx.x * 256 + threadIdx.x;
    if (e >= NE) return;
    int s = send[e], r = recv[e];
    const float* xs = x + (size_t)s * 6;
    const float* xr = x + (size_t)r * 6;
    float xs3 = xs[3], xr3 = xr[3];
    if (!(xs3 <= xr3)) return;                 // masked edge contributes nothing anywhere
    float d0 = xr[0] - xs[0], d1 = xr[1] - xs[1], d2 = xr[2] - xs[2];
    float d3 = xr3 - xs3,     d4 = xr[4] - xs[4], d5 = xr[5] - xs[5];
    float dist = sqrtf(d0 * d0 + d1 * d1 + d2 * d2);
    float inv = dist > 0.f ? 1.f / dist : 0.f;
    int slot = atomicAdd(ecnt, 1);
    float4* o = (float4*)(e8 + (size_t)slot * 8);
    o[0] = make_float4(d3, d4, d5, dist);
    o[1] = make_float4(d0 * inv, d1 * inv, d2 * inv, 0.f);
    cse[slot] = s;
    cre[slot] = r;
    atomicAdd(&deg[r], 1);
}

// ---------------- exclusive scan of deg -> rowptr (3 kernels) ----------------
__global__ __launch_bounds__(256) void scan_block_k(const int* __restrict__ deg,
    int* __restrict__ rowptr, int* __restrict__ bsum)
{
    __shared__ int s[256];
    const int tid = threadIdx.x;
    const int i = blockIdx.x * 256 + tid;
    const int v = (i < NN) ? deg[i] : 0;
    s[tid] = v;
    __syncthreads();
    for (int off = 1; off < 256; off <<= 1) {
        int t = (tid >= off) ? s[tid - off] : 0;
        __syncthreads();
        s[tid] += t;
        __syncthreads();
    }
    if (i < NN) rowptr[i] = s[tid] - v;        // block-local exclusive
    if (tid == 255) bsum[blockIdx.x] = s[255];
}

__global__ __launch_bounds__(256) void scan_top_k(int* __restrict__ bsum, int* __restrict__ boff)
{
    __shared__ int s[256];
    const int tid = threadIdx.x;
    const int v = (tid < NSB) ? bsum[tid] : 0;
    s[tid] = v;
    __syncthreads();
    for (int off = 1; off < 256; off <<= 1) {
        int t = (tid >= off) ? s[tid - off] : 0;
        __syncthreads();
        s[tid] += t;
        __syncthreads();
    }
    boff[tid] = s[tid] - v;                    // exclusive
}

__global__ __launch_bounds__(256) void scan_add_k(int* __restrict__ rowptr,
    const int* __restrict__ boff, int* __restrict__ cursor, const int* __restrict__ ecnt)
{
    const int i = blockIdx.x * 256 + threadIdx.x;
    if (i < NN) {
        const int r = rowptr[i] + boff[blockIdx.x];
        rowptr[i] = r;
        cursor[i] = r;
    }
    if (i == 0) rowptr[NN] = *ecnt;
}

// ---------------- fill CSR: edges sorted by recv ----------------
__global__ __launch_bounds__(256) void csr_fill_k(
    const int* __restrict__ cse, const int* __restrict__ cre, const int* __restrict__ ecnt,
    const float* __restrict__ e8, int* __restrict__ cursor,
    int* __restrict__ csr_s, int* __restrict__ csr_r, float* __restrict__ e8c)
{
    const int i = blockIdx.x * 256 + threadIdx.x;
    if (i >= *ecnt) return;
    const int r = cre[i];
    const int pos = atomicAdd(&cursor[r], 1);
    csr_s[pos] = cse[i];
    csr_r[pos] = r;
    const float4* src = (const float4*)&e8[(size_t)i * 8];
    float4* dst = (float4*)&e8c[(size_t)pos * 8];
    dst[0] = src[0]; dst[1] = src[1];
}

// ---------------- pack weights into MFMA B-fragment order ----------------
__global__ __launch_bounds__(256) void pack_w_k(
    const float* __restrict__ w, unsigned short* __restrict__ out,
    int KIN, int NT, int KT, int NCOL)
{
    int idx = blockIdx.x * 256 + threadIdx.x;
    int total = KT * NT * 512;
    if (idx >= total) return;
    int i = idx & 7;
    int lane = (idx >> 3) & 63;
    int t = idx >> 9;            // kt*NT + nt
    int nt = t % NT, kt = t / NT;
    int k = kt * 32 + (lane >> 4) * 8 + i;
    int n = nt * 16 + (lane & 15);
    out[idx] = (k < KIN) ? f2b(w[(size_t)k * NCOL + n]) : (unsigned short)0;
}

// ---------------- fp32 -> bf16 bulk convert ----------------
__global__ __launch_bounds__(256) void f2b_k(const float* __restrict__ in,
                                             unsigned short* __restrict__ out, int n8)
{
    int i = blockIdx.x * 256 + threadIdx.x;
    if (i >= n8) return;
    const float4 a = ((const float4*)in)[i * 2];
    const float4 b = ((const float4*)in)[i * 2 + 1];
    ushort8 o;
    o[0] = f2b(a.x); o[1] = f2b(a.y); o[2] = f2b(a.z); o[3] = f2b(a.w);
    o[4] = f2b(b.x); o[5] = f2b(b.y); o[6] = f2b(b.z); o[7] = f2b(b.w);
    ((ushort8*)out)[i] = o;
}

// ---------------- MFMA edge message MLP, CSR-ordered, run-segmented scatter ----------------
// in = [h[recv](HD), h[send](HD), e(7)] -> relu(·W1+b1) -> relu(·W2+b2), += into hout[recv]
// LDS: s_a / s_t / s_f share one union region (s_a dead after layer-1 reads) -> 4 blocks/CU.
template<int HD>
__global__ __launch_bounds__(256) void msg_mfma_k(
    const void* __restrict__ hin,            // HD=6: const float* x; HD=128: const ushort* h1b
    const float* __restrict__ e8c,
    const int* __restrict__ csr_s, const int* __restrict__ csr_r,
    const int* __restrict__ ecnt,
    const unsigned short* __restrict__ w1s, const float* __restrict__ b1,
    const unsigned short* __restrict__ w2s, const float* __restrict__ b2,
    float* __restrict__ hout)                                              // [NN,128] zeroed
{
    constexpr int KIN = 2 * HD + 7;                 // 19 or 263
    constexpr int KT1 = (KIN + 31) / 32;            // 1 or 9
    constexpr int K1S = KT1 * 32 + 8;               // LDS A stride: 40 or 296
    constexpr int ABY = 64 * K1S * 2;               // 5120 or 37888
    constexpr int TBY = 64 * 264 * 2;               // 33792
    constexpr int TOFF = (HD == 128) ? 0 : ABY;     // HD=128: s_t unions onto s_a
    constexpr int TOT  = (HD == 128) ? ((ABY > TBY) ? ABY : TBY) : (ABY + TBY);
    __shared__ char smem[TOT];
    auto s_a = (unsigned short (*)[K1S])smem;
    auto s_t = (unsigned short (*)[264])(smem + TOFF);
    auto s_f = (float (*)[130])(smem + TOFF);       // fp32 scatter buffer (33280 <= TBY)
    __shared__ int s_recv[64];

    const int Ec = *ecnt;
    const int e0 = blockIdx.x * 64;
    if (e0 >= Ec) return;
    const int tid = threadIdx.x;

    // ---- stage A ----
    if constexpr (HD == 128) {
        const unsigned short* hb = (const unsigned short*)hin;
        const int eg = tid >> 2, p = tid & 3;       // 4 threads per edge
        const int e = e0 + eg;
        const bool ev = e < Ec;
        int s = 0, r = 0;
        if (ev) { s = csr_s[e]; r = csr_r[e]; }
        if (p == 0) s_recv[eg] = r;
        const unsigned short* src = (p < 2) ? (hb + (size_t)r * 128 + p * 64)
                                            : (hb + (size_t)s * 128 + (p - 2) * 64);
        #pragma unroll
        for (int i = 0; i < 8; ++i) {
            ushort8 v = ushort8(0);
            if (ev) v = *(const ushort8*)(src + i * 8);
            *(ushort8*)&s_a[eg][p * 64 + i * 8] = v;
        }
        *(ushort8*)&s_a[eg][264 + p * 8] = ushort8(0);      // zero pad 264..295
        if (p == 0) {                                        // e-features cols 256..263
            ushort8 v = ushort8(0);
            if (ev) {
                const float4 ea = *(const float4*)&e8c[(size_t)e * 8];
                const float4 eb = *(const float4*)&e8c[(size_t)e * 8 + 4];
                v[0] = f2b(ea.x); v[1] = f2b(ea.y); v[2] = f2b(ea.z); v[3] = f2b(ea.w);
                v[4] = f2b(eb.x); v[5] = f2b(eb.y); v[6] = f2b(eb.z); v[7] = 0;
            }
            *(ushort8*)&s_a[eg][256] = v;
        }
    } else {
        if (tid < 64) {
            const float* xf = (const float*)hin;
            const int e = e0 + tid;
            const bool ev = e < Ec;
            int s = 0, r = 0;
            if (ev) { s = csr_s[e]; r = csr_r[e]; }
            s_recv[tid] = r;
            float a[19];
            #pragma unroll
            for (int c = 0; c < 19; ++c) a[c] = 0.f;
            if (ev) {
                const float* xr = xf + (size_t)r * 6;
                const float* xs = xf + (size_t)s * 6;
                #pragma unroll
                for (int c = 0; c < 6; ++c) { a[c] = xr[c]; a[6 + c] = xs[c]; }
                #pragma unroll
                for (int c = 0; c < 7; ++c) a[12 + c] = e8c[(size_t)e * 8 + c];
            }
            unsigned short u[40];
            #pragma unroll
            for (int c = 0; c < 19; ++c) u[c] = f2b(a[c]);
            #pragma unroll
            for (int c = 19; c < 40; ++c) u[c] = 0;
            #pragma unroll
            for (int c = 0; c < 5; ++c)
                *(ushort8*)&s_a[tid][c * 8] = *(ushort8*)&u[c * 8];
        }
    }
    __syncthreads();

    const int wv  = tid >> 6;        // wave 0..3
    const int lane = tid & 63;
    const int lhi = lane >> 4, llo = lane & 15;
    const short8* w1f = (const short8*)w1s;
    const short8* w2f = (const short8*)w2s;

    // ---- layer 1: [64,KIN] x [KIN,256]; wave wv owns cols wv*64..wv*64+63 ----
    f32x4 acc1[4][4];                                 // [q(ntile)][mt(rowtile)]
    {
        #pragma unroll
        for (int q = 0; q < 4; ++q) {
            const float bv = b1[(wv * 4 + q) * 16 + llo];
            #pragma unroll
            for (int mt = 0; mt < 4; ++mt) acc1[q][mt] = f32x4{bv, bv, bv, bv};
        }
        #pragma unroll
        for (int kt = 0; kt < KT1; ++kt) {
            short8 af[4];
            #pragma unroll
            for (int mt = 0; mt < 4; ++mt)
                af[mt] = *(const short8*)&s_a[mt * 16 + llo][kt * 32 + lhi * 8];
            #pragma unroll
            for (int q = 0; q < 4; ++q) {
                const short8 bf = w1f[(kt * 16 + wv * 4 + q) * 64 + lane];
                #pragma unroll
                for (int mt = 0; mt < 4; ++mt)
                    acc1[q][mt] = __builtin_amdgcn_mfma_f32_16x16x32_bf16(af[mt], bf, acc1[q][mt], 0, 0, 0);
            }
        }
    }
    __syncthreads();                 // all s_a reads done before s_t overwrites the region
    {
        // relu -> bf16 -> s_t
        #pragma unroll
        for (int q = 0; q < 4; ++q)
            #pragma unroll
            for (int mt = 0; mt < 4; ++mt)
                #pragma unroll
                for (int r = 0; r < 4; ++r)
                    s_t[mt * 16 + lhi * 4 + r][(wv * 4 + q) * 16 + llo] =
                        f2b(fmaxf(acc1[q][mt][r], 0.f));
    }
    __syncthreads();

    // ---- layer 2: [64,256] x [256,128]; wave wv owns cols wv*32..wv*32+31 ----
    {
        f32x4 acc[2][4];
        #pragma unroll
        for (int q = 0; q < 2; ++q) {
            const float bv = b2[(wv * 2 + q) * 16 + llo];
            #pragma unroll
            for (int mt = 0; mt < 4; ++mt) acc[q][mt] = f32x4{bv, bv, bv, bv};
        }
        #pragma unroll
        for (int kt = 0; kt < 8; ++kt) {
            short8 af[4];
            #pragma unroll
            for (int mt = 0; mt < 4; ++mt)
                af[mt] = *(const short8*)&s_t[mt * 16 + llo][kt * 32 + lhi * 8];
            #pragma unroll
            for (int q = 0; q < 2; ++q) {
                const short8 bf = w2f[(kt * 8 + wv * 2 + q) * 64 + lane];
                #pragma unroll
                for (int mt = 0; mt < 4; ++mt)
                    acc[q][mt] = __builtin_amdgcn_mfma_f32_16x16x32_bf16(af[mt], bf, acc[q][mt], 0, 0, 0);
            }
        }
        __syncthreads();            // all s_t reads complete before s_f overlay write
        #pragma unroll
        for (int q = 0; q < 2; ++q)
            #pragma unroll
            for (int mt = 0; mt < 4; ++mt)
                #pragma unroll
                for (int r = 0; r < 4; ++r)
                    s_f[mt * 16 + lhi * 4 + r][(wv * 2 + q) * 16 + llo] =
                        fmaxf(acc[q][mt][r], 0.f);
    }
    __syncthreads();

    // ---- run-segmented scatter: edges sorted by recv -> one atomic per run ----
    {
        const int c = tid & 127, hf = tid >> 7;
        int cur = -1; float run = 0.f;
        for (int i = 0; i < 32; ++i) {
            const int row = hf * 32 + i;
            if (e0 + row >= Ec) break;
            const int rv = s_recv[row];
            if (rv != cur) {
                if (cur >= 0) unsafeAtomicAdd(&hout[(size_t)cur * 128 + c], run);
                cur = rv; run = 0.f;
            }
            run += s_f[row][c];
        }
        if (cur >= 0) unsafeAtomicAdd(&hout[(size_t)cur * 128 + c], run);
    }
}

// ---------------- node update MLP via MFMA: 128 -> 128 -> 64 ----------------
__global__ __launch_bounds__(256) void upd_mfma_k(
    const float* __restrict__ hin,                                         // [NN,128] fp32
    const unsigned short* __restrict__ w1p, const float* __restrict__ b1,  // packed [4][8][64][8]
    const unsigned short* __restrict__ w2p, const float* __restrict__ b2,  // packed [4][4][64][8]
    float* __restrict__ hout)                                              // [NN,64]
{
    __shared__ unsigned short s_in[64][136];
    __shared__ unsigned short s_t[64][136];
    const int tid = threadIdx.x;
    const int n0 = blockIdx.x * 64;

    { // stage: 4 threads/node, 32 cols each, fp32 -> bf16
        const int ng = tid >> 2, p = tid & 3;
        const int n = n0 + ng;
        if (n < NN) {
            const float* src = hin + (size_t)n * 128 + p * 32;
            unsigned short u[32];
            #pragma unroll
            for (int k = 0; k < 8; ++k) {
                const float4 v = *(const float4*)(src + k * 4);
                u[k*4] = f2b(v.x); u[k*4+1] = f2b(v.y); u[k*4+2] = f2b(v.z); u[k*4+3] = f2b(v.w);
            }
            #pragma unroll
            for (int k = 0; k < 4; ++k)
                *(ushort8*)&s_in[ng][p * 32 + k * 8] = *(ushort8*)&u[k * 8];
        } else {
            #pragma unroll
            for (int k = 0; k < 4; ++k)
                *(ushort8*)&s_in[ng][p * 32 + k * 8] = ushort8(0);
        }
    }
    __syncthreads();

    const int wv = tid >> 6, lane = tid & 63, lhi = lane >> 4, llo = lane & 15;
    const short8* w1f = (const short8*)w1p;
    const short8* w2f = (const short8*)w2p;

    { // layer1: [64,128]x[128,128]; wave wv owns cols wv*32..+31
        f32x4 acc[2][4];
        #pragma unroll
        for (int q = 0; q < 2; ++q) {
            const float bv = b1[(wv * 2 + q) * 16 + llo];
            #pragma unroll
            for (int mt = 0; mt < 4; ++mt) acc[q][mt] = f32x4{bv, bv, bv, bv};
        }
        #pragma unroll
        for (int kt = 0; kt < 4; ++kt) {
            short8 af[4];
            #pragma unroll
            for (int mt = 0; mt < 4; ++mt)
                af[mt] = *(const short8*)&s_in[mt * 16 + llo][kt * 32 + lhi * 8];
            #pragma unroll
            for (int q = 0; q < 2; ++q) {
                const short8 bf = w1f[(kt * 8 + wv * 2 + q) * 64 + lane];
                #pragma unroll
                for (int mt = 0; mt < 4; ++mt)
                    acc[q][mt] = __builtin_amdgcn_mfma_f32_16x16x32_bf16(af[mt], bf, acc[q][mt], 0, 0, 0);
            }
        }
        #pragma unroll
        for (int q = 0; q < 2; ++q)
            #pragma unroll
            for (int mt = 0; mt < 4; ++mt)
                #pragma unroll
                for (int r = 0; r < 4; ++r)
                    s_t[mt * 16 + lhi * 4 + r][(wv * 2 + q) * 16 + llo] =
                        f2b(fmaxf(acc[q][mt][r], 0.f));
    }
    __syncthreads();

    { // layer2: [64,128]x[128,64]; wave wv owns cols wv*16..+15
        f32x4 acc[4];
        const float bv = b2[wv * 16 + llo];
        #pragma unroll
        for (int mt = 0; mt < 4; ++mt) acc[mt] = f32x4{bv, bv, bv, bv};
        #pragma unroll
        for (int kt = 0; kt < 4; ++kt) {
            short8 af[4];
            #pragma unroll
            for (int mt = 0; mt < 4; ++mt)
                af[mt] = *(const short8*)&s_t[mt * 16 + llo][kt * 32 + lhi * 8];
            const short8 bf = w2f[(kt * 4 + wv) * 64 + lane];
            #pragma unroll
            for (int mt = 0; mt < 4; ++mt)
                acc[mt] = __builtin_amdgcn_mfma_f32_16x16x32_bf16(af[mt], bf, acc[mt], 0, 0, 0);
        }
        #pragma unroll
        for (int mt = 0; mt < 4; ++mt)
            #pragma unroll
            for (int r = 0; r < 4; ++r) {
                const int n = n0 + mt * 16 + lhi * 4 + r;
                if (n < NN)
                    hout[(size_t)n * 64 + wv * 16 + llo] = fmaxf(acc[mt][r], 0.f);
            }
    }
}

// ---------------- SAGE: inline CSR gather-mean + MFMA transform + l2norm + pooled reduce ----------------
__global__ __launch_bounds__(256) void sage_node_k(
    const float* __restrict__ hu,                       // [NN,64]
    const int* __restrict__ rowptr, const int* __restrict__ csr_s,
    const int* __restrict__ seg,
    const unsigned short* __restrict__ wss, const float* __restrict__ sb,  // packed [4][8][64][8]
    float* __restrict__ pmax, float* __restrict__ psum, float* __restrict__ npn)
{
    __shared__ unsigned short s_in[64][136];
    __shared__ float s_g[64][130];
    __shared__ float s_inv[64];
    __shared__ int   s_seg[64];
    const int tid = threadIdx.x;
    const int n0 = blockIdx.x * 64;

    { // ---- stage: 4 threads/node, 16 cols each; gather neighbor mean from CSR ----
        const int ng = tid >> 2, p = tid & 3;
        const int n = n0 + ng;
        if (n < NN) {
            if (p == 0) s_seg[ng] = seg[n];
            const float* hr = hu + (size_t)n * 64 + p * 16;
            float a[16];
            #pragma unroll
            for (int k = 0; k < 4; ++k) {
                const float4 v = *(const float4*)(hr + k * 4);
                a[k*4] = v.x; a[k*4+1] = v.y; a[k*4+2] = v.z; a[k*4+3] = v.w;
            }
            float s[16];
            #pragma unroll
            for (int k = 0; k < 16; ++k) s[k] = 0.f;
            const int rb = rowptr[n], re = rowptr[n + 1];
            for (int e = rb; e < re; ++e) {
                const float* hs = hu + (size_t)csr_s[e] * 64 + p * 16;
                #pragma unroll
                for (int k = 0; k < 4; ++k) {
                    const float4 v = *(const float4*)(hs + k * 4);
                    s[k*4] += v.x; s[k*4+1] += v.y; s[k*4+2] += v.z; s[k*4+3] += v.w;
                }
            }
            const float inv = (re > rb) ? 1.f / (float)(re - rb) : 0.f;
            unsigned short uh[16], ua[16];
            #pragma unroll
            for (int k = 0; k < 16; ++k) { uh[k] = f2b(a[k]); ua[k] = f2b(s[k] * inv); }
            *(ushort8*)&s_in[ng][p * 16]          = *(ushort8*)&uh[0];
            *(ushort8*)&s_in[ng][p * 16 + 8]      = *(ushort8*)&uh[8];
            *(ushort8*)&s_in[ng][64 + p * 16]     = *(ushort8*)&ua[0];
            *(ushort8*)&s_in[ng][64 + p * 16 + 8] = *(ushort8*)&ua[8];
        } else {
            if (p == 0) s_seg[ng] = -1;
            *(ushort8*)&s_in[ng][p * 16]          = ushort8(0);
            *(ushort8*)&s_in[ng][p * 16 + 8]      = ushort8(0);
            *(ushort8*)&s_in[ng][64 + p * 16]     = ushort8(0);
            *(ushort8*)&s_in[ng][64 + p * 16 + 8] = ushort8(0);
        }
    }
    __syncthreads();

    const int wv = tid >> 6, lane = tid & 63, lhi = lane >> 4, llo = lane & 15;
    const short8* wf = (const short8*)wss;
    { // ---- [64,128] x [128,128] MFMA; wave wv owns cols wv*32..wv*32+31 ----
        f32x4 acc[2][4];
        #pragma unroll
        for (int q = 0; q < 2; ++q) {
            const float bv = sb[(wv * 2 + q) * 16 + llo];
            #pragma unroll
            for (int mt = 0; mt < 4; ++mt) acc[q][mt] = f32x4{bv, bv, bv, bv};
        }
        #pragma unroll
        for (int kt = 0; kt < 4; ++kt) {
            short8 af[4];
            #pragma unroll
            for (int mt = 0; mt < 4; ++mt)
                af[mt] = *(const short8*)&s_in[mt * 16 + llo][kt * 32 + lhi * 8];
            #pragma unroll
            for (int q = 0; q < 2; ++q) {
                const short8 bf = wf[(kt * 8 + wv * 2 + q) * 64 + lane];
                #pragma unroll
                for (int mt = 0; mt < 4; ++mt)
                    acc[q][mt] = __builtin_amdgcn_mfma_f32_16x16x32_bf16(af[mt], bf, acc[q][mt], 0, 0, 0);
            }
        }
        #pragma unroll
        for (int q = 0; q < 2; ++q)
            #pragma unroll
            for (int mt = 0; mt < 4; ++mt)
                #pragma unroll
                for (int r = 0; r < 4; ++r)
                    s_g[mt * 16 + lhi * 4 + r][(wv * 2 + q) * 16 + llo] = acc[q][mt][r];
    }
    __syncthreads();
    { // ---- l2 norm (pre-relu, fp32): 4 threads/row ----
        const int row = tid >> 2, p = tid & 3;
        float ss = 0.f;
        #pragma unroll
        for (int k = 0; k < 32; ++k) { const float v = s_g[row][p * 32 + k]; ss += v * v; }
        ss += __shfl_xor(ss, 1);
        ss += __shfl_xor(ss, 2);
        if (p == 0) s_inv[row] = rsqrtf(fmaxf(ss, 1e-12f));
    }
    __syncthreads();
    { // ---- run-segmented pooling: seg sorted -> one atomic pair per run per col ----
        const int c = tid & 127, hf = tid >> 7;
        int cur = -1; float rs = 0.f, rm = 0.f;     // g >= 0, so 0 is a valid max identity
        for (int i = 0; i < 32; ++i) {
            const int row = hf * 32 + i;
            if (n0 + row >= NN) break;
            const int sg = s_seg[row];
            const float g = fmaxf(s_g[row][c] * s_inv[row], 0.f);
            if (sg != cur) {
                if (cur >= 0) {
                    unsafeAtomicAdd(&psum[(size_t)cur * 128 + c], rs);
                    atomicMax((unsigned int*)&pmax[(size_t)cur * 128 + c], __float_as_uint(rm));
                }
                cur = sg; rs = 0.f; rm = 0.f;
            }
            rs += g; rm = fmaxf(rm, g);
        }
        if (cur >= 0) {
            unsafeAtomicAdd(&psum[(size_t)cur * 128 + c], rs);
            atomicMax((unsigned int*)&pmax[(size_t)cur * 128 + c], __float_as_uint(rm));
        }
    }
    if (tid == 0 || tid == 128) { // ---- npn: node counts per run ----
        const int hf = tid >> 7;
        int cur = -1; float cnt = 0.f;
        for (int i = 0; i < 32; ++i) {
            const int row = hf * 32 + i;
            if (n0 + row >= NN) break;
            const int sg = s_seg[row];
            if (sg != cur) { if (cur >= 0) unsafeAtomicAdd(&npn[cur], cnt); cur = sg; cnt = 0.f; }
            cnt += 1.f;
        }
        if (cur >= 0) unsafeAtomicAdd(&npn[cur], cnt);
    }
}

// ---------------- decoder + heads ----------------
__global__ __launch_bounds__(256) void dec_heads_k(
    const float* __restrict__ pmax, const float* __restrict__ psum, const float* __restrict__ npn,
    const float* __restrict__ d0w, const float* __restrict__ d0b,
    const float* __restrict__ g0, const float* __restrict__ be0,
    const float* __restrict__ m0, const float* __restrict__ v0,
    const float* __restrict__ d1w, const float* __restrict__ d1b,
    const float* __restrict__ g1, const float* __restrict__ be1,
    const float* __restrict__ m1, const float* __restrict__ v1,
    const float* __restrict__ lw0, const float* __restrict__ lb0,
    const float* __restrict__ lw1, const float* __restrict__ lb1,
    const float* __restrict__ lwo, const float* __restrict__ lbo,
    const float* __restrict__ aw0, const float* __restrict__ ab0,
    const float* __restrict__ aw1, const float* __restrict__ ab1,
    const float* __restrict__ awo, const float* __restrict__ abo,
    const float* __restrict__ sw0, const float* __restrict__ sb0,
    const float* __restrict__ sw1, const float* __restrict__ sb1,
    const float* __restrict__ swo, const float* __restrict__ sbo,
    const float* __restrict__ ascw, const float* __restrict__ ascb,
    float* __restrict__ out)
{
    __shared__ float z0[384];
    __shared__ float z1[1024];
    __shared__ float z2[512];
    __shared__ float ha[192];
    __shared__ float hb[192];
    __shared__ float fin[8];
    const int b = blockIdx.x, tid = threadIdx.x;
    if (tid < 128) {
        const float pm = pmax[(size_t)b * 128 + tid];
        const float ps = psum[(size_t)b * 128 + tid];
        const float nv = fmaxf(npn[b], 1.f);
        z0[tid] = pm; z0[128 + tid] = ps / nv; z0[256 + tid] = ps;
    }
    __syncthreads();
    {
        float acc[4] = { d0b[tid], d0b[tid + 256], d0b[tid + 512], d0b[tid + 768] };
        for (int k = 0; k < 384; ++k) {
            const float zk = z0[k];
            const float* wr = d0w + (size_t)k * 1024 + tid;
            acc[0] += zk * wr[0]; acc[1] += zk * wr[256]; acc[2] += zk * wr[512]; acc[3] += zk * wr[768];
        }
        #pragma unroll
        for (int i = 0; i < 4; ++i) {
            const int j = tid + 256 * i;
            float v = acc[i] > 0.f ? acc[i] : 0.15f * acc[i];
            v = (v - m0[j]) * (1.f / sqrtf(v0[j] + 1e-3f)) * g0[j] + be0[j];
            z1[j] = v;
        }
    }
    __syncthreads();
    {
        float acc[2] = { d1b[tid], d1b[tid + 256] };
        for (int k = 0; k < 1024; ++k) {
            const float zk = z1[k];
            const float* wr = d1w + (size_t)k * 512 + tid;
            acc[0] += zk * wr[0]; acc[1] += zk * wr[256];
        }
        #pragma unroll
        for (int i = 0; i < 2; ++i) {
            const int j = tid + 256 * i;
            float v = acc[i] > 0.f ? acc[i] : 0.15f * acc[i];
            v = (v - m1[j]) * (1.f / sqrtf(v1[j] + 1e-3f)) * g1[j] + be1[j];
            z2[j] = v;
        }
    }
    __syncthreads();
    if (tid < 192) {
        const int hd = tid >> 6, j = tid & 63;
        const float* w0 = hd == 0 ? lw0 : (hd == 1 ? aw0 : sw0);
        const float* b0 = hd == 0 ? lb0 : (hd == 1 ? ab0 : sb0);
        float acc = b0[j];
        for (int k = 0; k < 512; ++k) acc += z2[k] * w0[(size_t)k * 64 + j];
        ha[tid] = acc;
    }
    __syncthreads();
    if (tid < 192) {
        const int hd = tid >> 6, j = tid & 63;
        const float* w1p = hd == 0 ? lw1 : (hd == 1 ? aw1 : sw1);
        const float* b1p = hd == 0 ? lb1 : (hd == 1 ? ab1 : sb1);
        const float* src = &ha[hd * 64];
        float acc = b1p[j];
        for (int k = 0; k < 64; ++k) acc += src[k] * w1p[(size_t)k * 64 + j];
        hb[tid] = acc;
    }
    __syncthreads();
    if (tid < 5) {
        float acc;
        if (tid == 0) { acc = lbo[0]; for (int k = 0; k < 64; ++k) acc += hb[k] * lwo[k]; }
        else if (tid < 3) { const int c = tid - 1; acc = abo[c]; for (int k = 0; k < 64; ++k) acc += hb[64 + k] * awo[k * 2 + c]; }
        else { const int c = tid - 3; acc = sbo[c]; for (int k = 0; k < 64; ++k) acc += hb[128 + k] * swo[k * 2 + c]; }
        fin[tid] = acc;
    }
    __syncthreads();
    if (tid == 0) {
        const float a0 = fin[1], a1 = fin[2];
        const float q0 = a0 * ascw[0] + a1 * ascw[2] + ascb[0];
        const float q1 = a0 * ascw[1] + a1 * ascw[3] + ascb[1];
        const float zen = 1.f / (1.f + expf(-q0));
        const float azi = 1.f / (1.f + expf(-q1));
        const float PI = 3.14159265358979323846f;
        float* o = out + (size_t)b * 5;
        o[0] = fin[0];
        o[1] = zen * PI;
        o[2] = azi * 2.f * PI;
        o[3] = fabsf(fin[3]) + 1e-5f;
        o[4] = fabsf(fin[4]) + 1e-5f;
    }
}

extern "C" void kernel_launch(void* const* d_in, const int* in_sizes, int n_in,
                              void* d_out, int out_size, void* d_ws, size_t ws_size,
                              hipStream_t stream)
{
    const float* x    = (const float*)d_in[0];
    const int* send   = (const int*)d_in[1];
    const int* recv   = (const int*)d_in[2];
    const int* seg    = (const int*)d_in[3];
    const float* m0w1 = (const float*)d_in[4];
    const float* m0b1 = (const float*)d_in[5];
    const float* m0w2 = (const float*)d_in[6];
    const float* m0b2 = (const float*)d_in[7];
    const float* m1w1 = (const float*)d_in[8];
    const float* m1b1 = (const float*)d_in[9];
    const float* m1w2 = (const float*)d_in[10];
    const float* m1b2 = (const float*)d_in[11];
    const float* uw1  = (const float*)d_in[12];
    const float* ub1  = (const float*)d_in[13];
    const float* uw2  = (const float*)d_in[14];
    const float* ub2  = (const float*)d_in[15];
    const float* sgw  = (const float*)d_in[16];
    const float* sgb  = (const float*)d_in[17];
    const float* d0w  = (const float*)d_in[18];
    const float* d0b  = (const float*)d_in[19];
    const float* bn0g = (const float*)d_in[20];
    const float* bn0b = (const float*)d_in[21];
    const float* bn0m = (const float*)d_in[22];
    const float* bn0v = (const float*)d_in[23];
    const float* d1w  = (const float*)d_in[24];
    const float* d1b  = (const float*)d_in[25];
    const float* bn1g = (const float*)d_in[26];
    const float* bn1b = (const float*)d_in[27];
    const float* bn1m = (const float*)d_in[28];
    const float* bn1v = (const float*)d_in[29];
    const float* lw0  = (const float*)d_in[30];
    const float* lb0  = (const float*)d_in[31];
    const float* lw1  = (const float*)d_in[32];
    const float* lb1  = (const float*)d_in[33];
    const float* lwo  = (const float*)d_in[34];
    const float* lbo  = (const float*)d_in[35];
    const float* aw0  = (const float*)d_in[36];
    const float* ab0  = (const float*)d_in[37];
    const float* aw1  = (const float*)d_in[38];
    const float* ab1  = (const float*)d_in[39];
    const float* awo  = (const float*)d_in[40];
    const float* abo  = (const float*)d_in[41];
    const float* sw0  = (const float*)d_in[42];
    const float* sb0  = (const float*)d_in[43];
    const float* sw1  = (const float*)d_in[44];
    const float* sb1  = (const float*)d_in[45];
    const float* swo  = (const float*)d_in[46];
    const float* sbo  = (const float*)d_in[47];
    const float* ascw = (const float*)d_in[48];
    const float* ascb = (const float*)d_in[49];

    char* ws = (char*)d_ws;
    size_t off = 0;
    auto alloc = [&](size_t bytes) { void* p = ws + off; off = (off + bytes + 31) & ~(size_t)31; return p; };
    // zero-region: h1,h2,pmax,psum,npn contiguous
    float* h1   = (float*)alloc((size_t)NN * 128 * 4);
    float* h2   = (float*)alloc((size_t)NN * 128 * 4);
    float* pmax = (float*)alloc((size_t)NB * 128 * 4);
    float* psum = (float*)alloc((size_t)NB * 128 * 4);
    float* npn  = (float*)alloc((size_t)NB * 4);
    float* e8   = (float*)alloc((size_t)NE * 8 * 4);
    float* e8c  = (float*)alloc((size_t)NE * 8 * 4);
    int* cse    = (int*)alloc((size_t)NE * 4);
    int* cre    = (int*)alloc((size_t)NE * 4);
    int* csr_s  = (int*)alloc((size_t)NE * 4);
    int* csr_r  = (int*)alloc((size_t)NE * 4);
    int* deg    = (int*)alloc((size_t)NN * 4);
    int* rowptr = (int*)alloc((size_t)(NN + 1) * 4);
    int* cursor = (int*)alloc((size_t)NN * 4);
    int* bsum   = (int*)alloc(256 * 4);
    int* boff   = (int*)alloc(256 * 4);
    int* ecnt   = (int*)alloc(4);
    unsigned short* h1b  = (unsigned short*)alloc((size_t)NN * 128 * 2);
    unsigned short* w1s0 = (unsigned short*)alloc((size_t)1 * 16 * 512 * 2);
    unsigned short* w2s0 = (unsigned short*)alloc((size_t)8 * 8 * 512 * 2);
    unsigned short* w1s1 = (unsigned short*)alloc((size_t)9 * 16 * 512 * 2);
    unsigned short* w2s1 = (unsigned short*)alloc((size_t)8 * 8 * 512 * 2);
    unsigned short* wss  = (unsigned short*)alloc((size_t)4 * 8 * 512 * 2);
    unsigned short* wup1 = (unsigned short*)alloc((size_t)4 * 8 * 512 * 2);
    unsigned short* wup2 = (unsigned short*)alloc((size_t)4 * 4 * 512 * 2);
    float* hu = h1;                                   // [N,64] (h1 fp32 dead after f2b)

    hipMemsetAsync(h1, 0, ((size_t)NN * 256 + (size_t)NB * 257) * sizeof(float), stream);
    hipMemsetAsync(deg, 0, (size_t)NN * sizeof(int), stream);
    hipMemsetAsync(ecnt, 0, sizeof(int), stream);

    pack_w_k<<<(1 * 16 * 512 + 255) / 256, 256, 0, stream>>>(m0w1, w1s0, 19, 16, 1, 256);
    pack_w_k<<<(8 * 8 * 512 + 255) / 256, 256, 0, stream>>>(m0w2, w2s0, 256, 8, 8, 128);
    pack_w_k<<<(9 * 16 * 512 + 255) / 256, 256, 0, stream>>>(m1w1, w1s1, 263, 16, 9, 256);
    pack_w_k<<<(8 * 8 * 512 + 255) / 256, 256, 0, stream>>>(m1w2, w2s1, 256, 8, 8, 128);
    pack_w_k<<<(4 * 8 * 512 + 255) / 256, 256, 0, stream>>>(sgw, wss, 128, 8, 4, 128);
    pack_w_k<<<(4 * 8 * 512 + 255) / 256, 256, 0, stream>>>(uw1, wup1, 128, 8, 4, 128);
    pack_w_k<<<(4 * 4 * 512 + 255) / 256, 256, 0, stream>>>(uw2, wup2, 128, 4, 4, 64);

    edge_compact_k<<<(NE + 255) / 256, 256, 0, stream>>>(x, send, recv, e8, cse, cre, ecnt, deg);
    scan_block_k<<<NSB, 256, 0, stream>>>(deg, rowptr, bsum);
    scan_top_k<<<1, 256, 0, stream>>>(bsum, boff);
    scan_add_k<<<NSB, 256, 0, stream>>>(rowptr, boff, cursor, ecnt);
    csr_fill_k<<<(NE + 255) / 256, 256, 0, stream>>>(cse, cre, ecnt, e8, cursor, csr_s, csr_r, e8c);

    msg_mfma_k<6><<<NE / 64, 256, 0, stream>>>(x, e8c, csr_s, csr_r, ecnt, w1s0, m0b1, w2s0, m0b2, h1);
    f2b_k<<<(NN * 128 / 8 + 255) / 256, 256, 0, stream>>>(h1, h1b, NN * 128 / 8);
    msg_mfma_k<128><<<NE / 64, 256, 0, stream>>>(h1b, e8c, csr_s, csr_r, ecnt, w1s1, m1b1, w2s1, m1b2, h2);
    upd_mfma_k<<<(NN + 63) / 64, 256, 0, stream>>>(h2, wup1, ub1, wup2, ub2, hu);
    sage_node_k<<<(NN + 63) / 64, 256, 0, stream>>>(hu, rowptr, csr_s, seg, wss, sgb, pmax, psum, npn);
    dec_heads_k<<<NB, 256, 0, stream>>>(pmax, psum, npn,
        d0w, d0b, bn0g, bn0b, bn0m, bn0v,
        d1w, d1b, bn1g, bn1b, bn1m, bn1v,
        lw0, lb0, lw1, lb1, lwo, lbo,
        aw0, ab0, aw1, ab1, awo, abo,
        sw0, sb0, sw1, sb1, swo, sbo,
        ascw, ascb, (float*)d_out);
}